// Round 2
// 1608.207 us; speedup vs baseline: 1.1412x; 1.1412x over previous
//
#include <hip/hip_runtime.h>
#include <hip/hip_bf16.h>

#define HDIM 1024
#define BDIM 32
#define TDIM 64
#define SDIM 64
#define NBLK 256

typedef __attribute__((ext_vector_type(8))) short short8;
typedef __attribute__((ext_vector_type(4))) float f32x4;
typedef unsigned short ushort;
typedef unsigned int uint;

__device__ __forceinline__ float sigm(float x){ return 1.f/(1.f+expf(-x)); }
__device__ __forceinline__ ushort f2bf(float x){
  uint u = __float_as_uint(x);
  u = (u + 0x7FFF + ((u>>16)&1)) >> 16;   // RNE
  return (ushort)u;
}
#define MFMA16(a,b,c) __builtin_amdgcn_mfma_f32_16x16x32_bf16((a),(b),(c),0,0,0)
#define ALD(p)     __hip_atomic_load((p), __ATOMIC_RELAXED, __HIP_MEMORY_SCOPE_AGENT)
#define AST(p,v)   __hip_atomic_store((p),(v), __ATOMIC_RELAXED, __HIP_MEMORY_SCOPE_AGENT)

// ---------------- init: bf16 h seeds (parity 0 for both layers) ----------------
__global__ void init_state_kernel(const float* __restrict__ h0,
                                  ushort* __restrict__ hbuf){ // [4][32768]: h0p0,h0p1,h1p0,h1p1
  int i = blockIdx.x*256 + threadIdx.x;       // 0..65535
  int l = i >> 15, r = i & 32767;
  hbuf[(size_t)(l*2)*32768 + r] = f2bf(h0[i]);
}

__global__ void bar_init_kernel(int* flags){
  flags[threadIdx.x] = 0;         // arrival flags [0..255]
  flags[256 + threadIdx.x] = 0;   // incl. release word at flags[320]
}

// ---------------- fp32 -> bf16 cast (vector x4) ----------------
__global__ void cast_kernel(const float* __restrict__ src, ushort* __restrict__ dst, int n4){
  int i = blockIdx.x*256 + threadIdx.x;
  if(i < n4){
    float4 v = ((const float4*)src)[i];
    ushort4 o; o.x=f2bf(v.x); o.y=f2bf(v.y); o.z=f2bf(v.z); o.w=f2bf(v.w);
    ((ushort4*)dst)[i] = o;
  }
}

// ---------------- contexts transpose: [32][64][1024] f32 -> [32][1024][64] bf16 ----
__global__ void transpose_ctx_kernel(const float* __restrict__ ctx, ushort* __restrict__ ctxT){
  int b = blockIdx.y;
  int n = blockIdx.x*64 + (threadIdx.x & 63);
  int s0 = (threadIdx.x >> 6) * 16;
  for(int s=s0; s<s0+16; s++){
    float v = ctx[((size_t)b*SDIM + s)*HDIM + n];
    ctxT[((size_t)b*HDIM + n)*SDIM + s] = f2bf(v);
  }
}

// ---------------- combined biases ----------------
__global__ void bias_kernel(const float* __restrict__ b_ih, const float* __restrict__ b_hh,
                            float* __restrict__ bias0, float* __restrict__ bias1){
  int i = blockIdx.x*256 + threadIdx.x;   // 0..4095
  bias0[i] = b_ih[i] + b_hh[i];
  bias1[i] = b_ih[4096+i] + b_hh[4096+i];
}

// ---------------- embedding gather + bf16 cast ----------------
__global__ void embed_kernel(const int* __restrict__ tokens,
                             const float* __restrict__ emb,
                             ushort* __restrict__ Xb){
  int tb = blockIdx.x;
  int tok = tokens[tb];
  const float4* src = (const float4*)(emb + (size_t)tok*HDIM);
  ushort4* dst = (ushort4*)(Xb + (size_t)tb*HDIM);
  float4 v = src[threadIdx.x];
  ushort4 o; o.x=f2bf(v.x); o.y=f2bf(v.y); o.z=f2bf(v.z); o.w=f2bf(v.w);
  dst[threadIdx.x] = o;
}

// ---------------- big MFMA GEMM: C = act(A@B^T + bias) ----------------
// act: 0 = fp32 store, 1 = tanh fp32 store, 2 = bf16 store
__global__ __launch_bounds__(256) void gemm_mfma_bt(
    const ushort* __restrict__ A0, const ushort* __restrict__ A1, int lda, int KSPLIT,
    const ushort* __restrict__ B, int ldb,
    const float* __restrict__ bias,
    float* __restrict__ C, int ldc, int K, int act){
  __shared__ ushort As[64][40];
  __shared__ ushort Bs[64][40];
  const int bm = blockIdx.y*64, bn = blockIdx.x*64;
  const int tid = threadIdx.x, w = tid>>6, lane = tid&63;
  const int quad = lane>>4, l16 = lane&15;
  const int mh = (w>>1)*32, nh = (w&1)*32;
  const int arow = tid>>2, aseg = (tid&3)*8;
  f32x4 acc[2][2];
  #pragma unroll
  for(int i=0;i<2;i++)
    #pragma unroll
    for(int j=0;j<2;j++) acc[i][j] = (f32x4){0.f,0.f,0.f,0.f};

  for(int k0=0;k0<K;k0+=32){
    int gk = k0 + aseg;
    const ushort* ap = (gk < KSPLIT) ? (A0 + (size_t)(bm+arow)*lda + gk)
                                     : (A1 + (size_t)(bm+arow)*lda + (gk - KSPLIT));
    *(float4*)&As[arow][aseg] = *(const float4*)ap;
    *(float4*)&Bs[arow][aseg] = *(const float4*)(B + (size_t)(bn+arow)*ldb + k0 + aseg);
    __syncthreads();
    short8 a0 = *(const short8*)&As[mh + l16][quad*8];
    short8 a1 = *(const short8*)&As[mh + 16 + l16][quad*8];
    short8 b0 = *(const short8*)&Bs[nh + l16][quad*8];
    short8 b1 = *(const short8*)&Bs[nh + 16 + l16][quad*8];
    acc[0][0] = MFMA16(a0, b0, acc[0][0]);
    acc[0][1] = MFMA16(a0, b1, acc[0][1]);
    acc[1][0] = MFMA16(a1, b0, acc[1][0]);
    acc[1][1] = MFMA16(a1, b1, acc[1][1]);
    __syncthreads();
  }
  #pragma unroll
  for(int mi=0;mi<2;mi++){
    #pragma unroll
    for(int r=0;r<4;r++){
      int row = bm + mh + mi*16 + quad*4 + r;
      #pragma unroll
      for(int ni=0;ni<2;ni++){
        int col = bn + nh + ni*16 + l16;
        float v = acc[mi][ni][r];
        if(bias) v += bias[col];
        if(act==1) v = tanhf(v);
        if(act==2) ((ushort*)C)[(size_t)row*ldc + col] = f2bf(v);
        else       C[(size_t)row*ldc + col] = v;
      }
    }
  }
}

// ---------------- skewed persistent LSTM scan ----------------
// r4-proven lockstep architecture + software-pipeline skew (65 phases).
// Fan-in/fan-out barrier: arrival flags (256 words, parallel stores) are
// read each round by ONE aggregator wave (block 0, coalesced
// consecutive-address loads), which publishes a single release word on its
// own cache line; every block polls that one word with ONE thread.
// Replaces the 64-thread x 4-scattered-agent-dword poll per block (~16K
// cache-bypass line transactions per round grid-wide) that saturated the
// coherence fabric.
__global__ void lstm_skew(
    const ushort* __restrict__ Whh0b,   // [4096][1024] bf16
    const ushort* __restrict__ Wih1b,   // [4096][1024]
    const ushort* __restrict__ Whh1b,   // [4096][1024]
    const float*  __restrict__ G0,      // [T*32][4096] fp32 (bias0 folded)
    const float*  __restrict__ bias1c,  // [4096]
    const float*  __restrict__ c0in,    // [2][32][1024]
    ushort* __restrict__ hbuf,          // [4][32768]: h0p0,h0p1,h1p0,h1p1
    ushort* __restrict__ inp_bf,        // [T*32][1024]
    float*  __restrict__ outstate,      // h[2][32][1024] then c[2][32][1024]
    int* __restrict__ flags){           // [512]: [0..255] arrival, [320] release
  extern __shared__ char smem[];
  ushort (*W0s)[1032]   = (ushort(*)[1032])smem;                   // 33024 B
  ushort (*W1s)[2056]   = (ushort(*)[2056])(smem + 33024);         // 65792 B
  float (*gred0)[32][17] = (float(*)[32][17])(smem + 98816);       // 8704 B
  float (*gred1)[32][17] = (float(*)[32][17])(smem + 107520);      // 8704 B
  float (*cloc0)[4]      = (float(*)[4])(smem + 116224);           // 512 B
  float (*cloc1)[4]      = (float(*)[4])(smem + 116736);           // 512 B

  const int tid = threadIdx.x, w = tid>>6, lane = tid&63;
  const int quad = lane>>4, l16 = lane&15;
  const int blk = blockIdx.x;
  const int j0 = blk*4;

  // ---- load weight slices into LDS (held for all phases) — r4 verbatim ----
  {
    int r = tid>>4, seg = tid&15;                       // 16 rows x 16 segments
    int wr = (r>>2)*1024 + j0 + (r&3);                  // gate-major weight row
    const ushort* s0 = Whh0b + (size_t)wr*1024 + seg*64;
    const ushort* s1 = Wih1b + (size_t)wr*1024 + seg*64;
    const ushort* s2 = Whh1b + (size_t)wr*1024 + seg*64;
    #pragma unroll
    for(int u=0; u<64; u+=8){
      *(short8*)&W0s[r][seg*64+u]       = *(const short8*)(s0+u);
      *(short8*)&W1s[r][seg*64+u]       = *(const short8*)(s1+u);
      *(short8*)&W1s[r][1024+seg*64+u]  = *(const short8*)(s2+u);
    }
  }
  if(tid < 128){
    int b = tid>>2, jj = tid&3;
    cloc0[b][jj] = c0in[b*1024 + j0 + jj];
    cloc1[b][jj] = c0in[32768 + b*1024 + j0 + jj];
  }
  // loop-invariant bias1 in registers (layer-1 cell threads: tid 64..127)
  float2 pbI={0,0}, pbF={0,0}, pbG={0,0}, pbO={0,0};
  if(tid >= 64 && tid < 128){
    const float* br = bias1c + j0 + ((tid-64)&1)*2;
    pbI = *(const float2*)(br);
    pbF = *(const float2*)(br+1024);
    pbG = *(const float2*)(br+2048);
    pbO = *(const float2*)(br+3072);
  }
  __syncthreads();

  ushort* h0b[2] = { hbuf,            hbuf + 32768 };
  ushort* h1b[2] = { hbuf + 65536,    hbuf + 98304 };

  for(int p=0; p<=TDIM; p++){
    const int par = p&1, nxt = par^1;
    // G0 prefetch for layer0 step p (overlaps MFMA issue)
    float2 pgI={0,0}, pgF={0,0}, pgG={0,0}, pgO={0,0};
    if(p < TDIM && tid < 64){
      const float* g0r = G0 + (size_t)(p*32+(tid>>1))*4096 + j0 + (tid&1)*2;
      pgI = *(const float2*)(g0r);
      pgF = *(const float2*)(g0r+1024);
      pgG = *(const float2*)(g0r+2048);
      pgO = *(const float2*)(g0r+3072);
    }
    // ---- MFMA layer0 step p: gates0 = h0(p) @ W0s^T (K-split across waves) ----
    if(p < TDIM){
      const ushort* hsrc = h0b[par];
      f32x4 acc0 = {0,0,0,0}, acc1 = {0,0,0,0};
      int kbase = w*256;
      #pragma unroll
      for(int kc=0;kc<8;kc++){
        int k = kbase + kc*32 + quad*8;
        short8 bfrag = *(const short8*)&W0s[l16][k];
        short8 af0 = *(const short8*)(hsrc + (size_t)l16*1024 + k);
        short8 af1 = *(const short8*)(hsrc + (size_t)(l16+16)*1024 + k);
        acc0 = MFMA16(af0, bfrag, acc0);
        acc1 = MFMA16(af1, bfrag, acc1);
      }
      #pragma unroll
      for(int r=0;r<4;r++){
        gred0[w][quad*4+r][l16]    = acc0[r];
        gred0[w][16+quad*4+r][l16] = acc1[r];
      }
    }
    // ---- MFMA layer1 step p-1: gates1 = [h0(p) | h1(p-1)] @ W1s^T ----
    if(p > 0){
      f32x4 acc0 = {0,0,0,0}, acc1 = {0,0,0,0};
      int kbase = w*512;
      #pragma unroll
      for(int kc=0;kc<16;kc++){
        int k = kbase + kc*32 + quad*8;
        short8 bfrag = *(const short8*)&W1s[l16][k];
        const ushort* hsrc = (k < 1024) ? (h0b[par] + k) : (h1b[nxt] + (k-1024));
        short8 af0 = *(const short8*)(hsrc + (size_t)l16*1024);
        short8 af1 = *(const short8*)(hsrc + (size_t)(l16+16)*1024);
        acc0 = MFMA16(af0, bfrag, acc0);
        acc1 = MFMA16(af1, bfrag, acc1);
      }
      #pragma unroll
      for(int r=0;r<4;r++){
        gred1[w][quad*4+r][l16]    = acc0[r];
        gred1[w][16+quad*4+r][l16] = acc1[r];
      }
    }
    __syncthreads();
    // ---- layer0 cell (wave 0) ----
    if(p < TDIM && tid < 64){
      int b = tid>>1, j2 = (tid&1)*2;
      ushort hv[2];
      #pragma unroll
      for(int u=0;u<2;u++){
        int jj = j2+u;
        float gi = u ? pgI.y : pgI.x;
        float gf = u ? pgF.y : pgF.x;
        float gg = u ? pgG.y : pgG.x;
        float go = u ? pgO.y : pgO.x;
        #pragma unroll
        for(int ww=0;ww<4;ww++){
          gi += gred0[ww][b][jj];    gf += gred0[ww][b][4+jj];
          gg += gred0[ww][b][8+jj];  go += gred0[ww][b][12+jj];
        }
        float c = cloc0[b][jj];
        float c1 = sigm(gf)*c + sigm(gi)*tanhf(gg);
        float h1 = sigm(go)*tanhf(c1);
        cloc0[b][jj] = c1;
        hv[u] = f2bf(h1);
        if(p==TDIM-1){
          outstate[b*1024 + j0 + jj] = h1;          // hT layer0
          outstate[65536 + b*1024 + j0 + jj] = c1;  // cT layer0
        }
      }
      uint pk = (uint)hv[0] | ((uint)hv[1] << 16);
      AST((uint*)(h0b[nxt] + b*1024 + j0 + j2), pk);
    }
    // ---- layer1 cell (wave 1), step t = p-1 ----
    if(p > 0 && tid >= 64 && tid < 128){
      int ct = tid-64;
      int b = ct>>1, j2 = (ct&1)*2;
      ushort hv[2];
      #pragma unroll
      for(int u=0;u<2;u++){
        int jj = j2+u;
        float gi = u ? pbI.y : pbI.x;
        float gf = u ? pbF.y : pbF.x;
        float gg = u ? pbG.y : pbG.x;
        float go = u ? pbO.y : pbO.x;
        #pragma unroll
        for(int ww=0;ww<4;ww++){
          gi += gred1[ww][b][jj];    gf += gred1[ww][b][4+jj];
          gg += gred1[ww][b][8+jj];  go += gred1[ww][b][12+jj];
        }
        float c = cloc1[b][jj];
        float c1 = sigm(gf)*c + sigm(gi)*tanhf(gg);
        float h1 = sigm(go)*tanhf(c1);
        cloc1[b][jj] = c1;
        hv[u] = f2bf(h1);
        inp_bf[(size_t)((p-1)*32+b)*1024 + j0 + jj] = hv[u];
        if(p==TDIM){
          outstate[32768 + b*1024 + j0 + jj] = h1;          // hT layer1
          outstate[98304 + b*1024 + j0 + jj] = c1;          // cT layer1
        }
      }
      uint pk = (uint)hv[0] | ((uint)hv[1] << 16);
      AST((uint*)(h1b[par] + b*1024 + j0 + j2), pk);
    }
    if(p == TDIM) break;                 // last phase: kernel end flushes
    // ---- fan-in/fan-out barrier ----
    __syncthreads();                     // drains h stores + gred reuse
    const int target = p+1;
    if(tid==0){ __threadfence(); AST(&flags[blk], target); }
    if(blk==0 && tid<64){
      // aggregator: 64 lanes, 4 coalesced consecutive-address loads/round
      while(true){
        int v0 = ALD(&flags[tid]);
        int v1 = ALD(&flags[tid+64]);
        int v2 = ALD(&flags[tid+128]);
        int v3 = ALD(&flags[tid+192]);
        int mn = min(min(v0,v1),min(v2,v3));
        if(__all(mn >= target)) break;
        __builtin_amdgcn_s_sleep(2);
      }
      if(tid==0) AST(&flags[320], target);   // release (own cache line)
    }
    if(tid==0){
      while(ALD(&flags[320]) < target) __builtin_amdgcn_s_sleep(2);
      __threadfence();                   // invalidate caches before reading peers' h
    }
    __syncthreads();
  }
}

// ---------------- MFMA attention: block = (t-chunk of 16, b) ----------------
__global__ __launch_bounds__(256) void attn_mfma(
    const ushort* __restrict__ gamma_bf, // [2048][1024] rows t*32+b
    const ushort* __restrict__ ctxb,     // [32][64][1024] bf16
    const ushort* __restrict__ ctxT,     // [32][1024][64] bf16
    ushort* __restrict__ ctx_out){       // [2048][1024] bf16
  const int b = blockIdx.y, t0 = blockIdx.x*16;
  const int tid = threadIdx.x, w = tid>>6, lane = tid&63;
  const int quad = lane>>4, l16 = lane&15;
  __shared__ float S[16][68];
  __shared__ ushort Pb[16][72];
  {
    f32x4 acc = {0,0,0,0};
    const ushort* arow = gamma_bf + ((size_t)(t0+l16)*32 + b)*1024;
    const ushort* brow = ctxb + ((size_t)b*SDIM + w*16 + l16)*1024;
    #pragma unroll 8
    for(int kc=0;kc<32;kc++){
      short8 af = *(const short8*)(arow + kc*32 + quad*8);
      short8 bf = *(const short8*)(brow + kc*32 + quad*8);
      acc = MFMA16(af, bf, acc);
    }
    #pragma unroll
    for(int r=0;r<4;r++) S[quad*4+r][w*16+l16] = acc[r];
  }
  __syncthreads();
  if(tid < 16){
    float mx = -1e30f;
    for(int s=0;s<SDIM;s++) mx = fmaxf(mx, S[tid][s]);
    float sum = 0.f;
    for(int s=0;s<SDIM;s++) sum += expf(S[tid][s]-mx);
    float inv = 1.f/sum;
    for(int s=0;s<SDIM;s++) Pb[tid][s] = f2bf(expf(S[tid][s]-mx)*inv);
  }
  __syncthreads();
  const ushort* bbase = ctxT + ((size_t)b*HDIM + w*256)*SDIM;
  for(int nt=0; nt<16; nt++){
    f32x4 acc = {0,0,0,0};
    #pragma unroll
    for(int kc=0;kc<2;kc++){
      short8 af = *(const short8*)&Pb[l16][kc*32 + quad*8];
      short8 bf = *(const short8*)(bbase + (size_t)(nt*16+l16)*SDIM + kc*32 + quad*8);
      acc = MFMA16(af, bf, acc);
    }
    int n = w*256 + nt*16 + l16;
    #pragma unroll
    for(int r=0;r<4;r++){
      int t = t0 + quad*4 + r;
      ctx_out[((size_t)t*32 + b)*1024 + n] = f2bf(acc[r]);
    }
  }
}

extern "C" void kernel_launch(void* const* d_in, const int* in_sizes, int n_in,
                              void* d_out, int out_size, void* d_ws, size_t ws_size,
                              hipStream_t stream){
  const int*   tokens   = (const int*)  d_in[0];
  const float* h0       = (const float*)d_in[1];
  const float* c0       = (const float*)d_in[2];
  const float* contexts = (const float*)d_in[3];
  const float* emb      = (const float*)d_in[4];
  const float* W_ih     = (const float*)d_in[5];   // [2,4H,H]
  const float* W_hh     = (const float*)d_in[6];
  const float* b_ih     = (const float*)d_in[7];   // [2,4H]
  const float* b_hh     = (const float*)d_in[8];
  const float* W_in     = (const float*)d_in[9];   // [H,H]
  const float* b_in     = (const float*)d_in[10];
  const float* W_out    = (const float*)d_in[11];  // [H,2H]
  const float* b_out    = (const float*)d_in[12];

  float* out = (float*)d_out;
  const int TB = TDIM*BDIM;                        // 2048

  // ---- workspace layout ----
  char* wp = (char*)d_ws;
  float* G0      = (float*)wp;  wp += (size_t)TB*4*HDIM*4;          // 33.5 MB
  float* bias0c  = (float*)wp;  wp += 4096*4;
  float* bias1c  = (float*)wp;  wp += 4096*4;
  int*   flags   = (int*)wp;    wp += 2048;                         // 512 ints
  ushort* X_bf   = (ushort*)wp; wp += (size_t)TB*HDIM*2;
  ushort* Wih0b  = (ushort*)wp; wp += (size_t)4*HDIM*HDIM*2;
  ushort* Whh0b  = (ushort*)wp; wp += (size_t)4*HDIM*HDIM*2;
  ushort* Wih1b  = (ushort*)wp; wp += (size_t)4*HDIM*HDIM*2;
  ushort* Whh1b  = (ushort*)wp; wp += (size_t)4*HDIM*HDIM*2;
  ushort* Winb   = (ushort*)wp; wp += (size_t)HDIM*HDIM*2;
  ushort* Woutb  = (ushort*)wp; wp += (size_t)HDIM*2*HDIM*2;
  ushort* inp_bf = (ushort*)wp; wp += (size_t)TB*HDIM*2;
  ushort* hbuf   = (ushort*)wp; wp += (size_t)4*BDIM*HDIM*2;
  ushort* ctxb_bf= (ushort*)wp; wp += (size_t)BDIM*SDIM*HDIM*2;
  ushort* ctxT_bf= (ushort*)wp; wp += (size_t)BDIM*SDIM*HDIM*2;
  ushort* gammaB = (ushort*)G0;                                     // overlay
  ushort* ctx_bf = X_bf;                                            // overlay

  // ---- prep ----
  init_state_kernel<<<256,256,0,stream>>>(h0, hbuf);
  bar_init_kernel<<<1,256,0,stream>>>(flags);
  cast_kernel<<<4096,256,0,stream>>>(W_ih,                       Wih0b, 4*HDIM*HDIM/4);
  cast_kernel<<<4096,256,0,stream>>>(W_hh,                       Whh0b, 4*HDIM*HDIM/4);
  cast_kernel<<<4096,256,0,stream>>>(W_ih + (size_t)4*HDIM*HDIM, Wih1b, 4*HDIM*HDIM/4);
  cast_kernel<<<4096,256,0,stream>>>(W_hh + (size_t)4*HDIM*HDIM, Whh1b, 4*HDIM*HDIM/4);
  cast_kernel<<<1024,256,0,stream>>>(W_in,  Winb,  HDIM*HDIM/4);
  cast_kernel<<<2048,256,0,stream>>>(W_out, Woutb, HDIM*2*HDIM/4);
  cast_kernel<<<2048,256,0,stream>>>(contexts, ctxb_bf, BDIM*SDIM*HDIM/4);
  transpose_ctx_kernel<<<dim3(16,32),256,0,stream>>>(contexts, ctxT_bf);
  bias_kernel<<<16,256,0,stream>>>(b_ih, b_hh, bias0c, bias1c);
  embed_kernel<<<TB,256,0,stream>>>(tokens, emb, X_bf);

  // ---- G0 = X @ Wih0^T + (b_ih0+b_hh0)  [2048,4096] fp32 ----
  gemm_mfma_bt<<<dim3(4*HDIM/64, TB/64),256,0,stream>>>(
      X_bf, X_bf, HDIM, HDIM, Wih0b, HDIM, bias0c, G0, 4*HDIM, HDIM, 0);

  // ---- skewed persistent scan (1 dispatch, 65 phases) ----
  lstm_skew<<<NBLK,256,117248,stream>>>(
      Whh0b, Wih1b, Whh1b, G0, bias1c, c0,
      hbuf, inp_bf, out + (size_t)TB*HDIM, flags);

  // ---- gamma = inp @ W_in^T + b_in -> bf16 (overlays G0) ----
  gemm_mfma_bt<<<dim3(HDIM/64, TB/64),256,0,stream>>>(
      inp_bf, inp_bf, HDIM, HDIM, Winb, HDIM, b_in, (float*)gammaB, HDIM, HDIM, 2);

  // ---- attention (MFMA) ----
  attn_mfma<<<dim3(4,32),256,0,stream>>>(gammaB, ctxb_bf, ctxT_bf, ctx_bf);

  // ---- out = tanh([ctx|inp] @ W_out^T + b_out) -> d_out ----
  gemm_mfma_bt<<<dim3(HDIM/64, TB/64),256,0,stream>>>(
      ctx_bf, inp_bf, HDIM, HDIM, Woutb, 2*HDIM, b_out, out, HDIM, 2*HDIM, 1);
}

// Round 3
// 1005.881 us; speedup vs baseline: 1.8246x; 1.5988x over previous
//
#include <hip/hip_runtime.h>
#include <hip/hip_bf16.h>

#define HDIM 1024
#define BDIM 32
#define TDIM 64
#define SDIM 64
#define NBLK 256

typedef __attribute__((ext_vector_type(8))) short short8;
typedef __attribute__((ext_vector_type(4))) float f32x4;
typedef unsigned short ushort;
typedef unsigned int uint;

__device__ __forceinline__ float sigm(float x){ return 1.f/(1.f+expf(-x)); }
__device__ __forceinline__ ushort f2bf(float x){
  uint u = __float_as_uint(x);
  u = (u + 0x7FFF + ((u>>16)&1)) >> 16;   // RNE
  return (ushort)u;
}
#define MFMA16(a,b,c) __builtin_amdgcn_mfma_f32_16x16x32_bf16((a),(b),(c),0,0,0)
#define ALD(p)     __hip_atomic_load((p), __ATOMIC_RELAXED, __HIP_MEMORY_SCOPE_AGENT)
#define AST(p,v)   __hip_atomic_store((p),(v), __ATOMIC_RELAXED, __HIP_MEMORY_SCOPE_AGENT)

// ---------------- init: bf16 h seeds (parity 0 for both layers) ----------------
__global__ void init_state_kernel(const float* __restrict__ h0,
                                  ushort* __restrict__ hbuf){ // [4][32768]: h0p0,h0p1,h1p0,h1p1
  int i = blockIdx.x*256 + threadIdx.x;       // 0..65535
  int l = i >> 15, r = i & 32767;
  hbuf[(size_t)(l*2)*32768 + r] = f2bf(h0[i]);
}

__global__ void bar_init_kernel(int* flags){
  for(int i=threadIdx.x; i<1024; i+=256) flags[i] = 0;  // arrivals [0..255], release replicas [512..1023]
}

// ---------------- fp32 -> bf16 cast (vector x4) ----------------
__global__ void cast_kernel(const float* __restrict__ src, ushort* __restrict__ dst, int n4){
  int i = blockIdx.x*256 + threadIdx.x;
  if(i < n4){
    float4 v = ((const float4*)src)[i];
    ushort4 o; o.x=f2bf(v.x); o.y=f2bf(v.y); o.z=f2bf(v.z); o.w=f2bf(v.w);
    ((ushort4*)dst)[i] = o;
  }
}

// ---------------- contexts transpose: [32][64][1024] f32 -> [32][1024][64] bf16 ----
__global__ void transpose_ctx_kernel(const float* __restrict__ ctx, ushort* __restrict__ ctxT){
  int b = blockIdx.y;
  int n = blockIdx.x*64 + (threadIdx.x & 63);
  int s0 = (threadIdx.x >> 6) * 16;
  for(int s=s0; s<s0+16; s++){
    float v = ctx[((size_t)b*SDIM + s)*HDIM + n];
    ctxT[((size_t)b*HDIM + n)*SDIM + s] = f2bf(v);
  }
}

// ---------------- combined biases ----------------
__global__ void bias_kernel(const float* __restrict__ b_ih, const float* __restrict__ b_hh,
                            float* __restrict__ bias0, float* __restrict__ bias1){
  int i = blockIdx.x*256 + threadIdx.x;   // 0..4095
  bias0[i] = b_ih[i] + b_hh[i];
  bias1[i] = b_ih[4096+i] + b_hh[4096+i];
}

// ---------------- embedding gather + bf16 cast ----------------
__global__ void embed_kernel(const int* __restrict__ tokens,
                             const float* __restrict__ emb,
                             ushort* __restrict__ Xb){
  int tb = blockIdx.x;
  int tok = tokens[tb];
  const float4* src = (const float4*)(emb + (size_t)tok*HDIM);
  ushort4* dst = (ushort4*)(Xb + (size_t)tb*HDIM);
  float4 v = src[threadIdx.x];
  ushort4 o; o.x=f2bf(v.x); o.y=f2bf(v.y); o.z=f2bf(v.z); o.w=f2bf(v.w);
  dst[threadIdx.x] = o;
}

// ---------------- big MFMA GEMM: C = act(A@B^T + bias) ----------------
// act: 0 = fp32 store, 1 = tanh fp32 store, 2 = bf16 store
__global__ __launch_bounds__(256) void gemm_mfma_bt(
    const ushort* __restrict__ A0, const ushort* __restrict__ A1, int lda, int KSPLIT,
    const ushort* __restrict__ B, int ldb,
    const float* __restrict__ bias,
    float* __restrict__ C, int ldc, int K, int act){
  __shared__ ushort As[64][40];
  __shared__ ushort Bs[64][40];
  const int bm = blockIdx.y*64, bn = blockIdx.x*64;
  const int tid = threadIdx.x, w = tid>>6, lane = tid&63;
  const int quad = lane>>4, l16 = lane&15;
  const int mh = (w>>1)*32, nh = (w&1)*32;
  const int arow = tid>>2, aseg = (tid&3)*8;
  f32x4 acc[2][2];
  #pragma unroll
  for(int i=0;i<2;i++)
    #pragma unroll
    for(int j=0;j<2;j++) acc[i][j] = (f32x4){0.f,0.f,0.f,0.f};

  for(int k0=0;k0<K;k0+=32){
    int gk = k0 + aseg;
    const ushort* ap = (gk < KSPLIT) ? (A0 + (size_t)(bm+arow)*lda + gk)
                                     : (A1 + (size_t)(bm+arow)*lda + (gk - KSPLIT));
    *(float4*)&As[arow][aseg] = *(const float4*)ap;
    *(float4*)&Bs[arow][aseg] = *(const float4*)(B + (size_t)(bn+arow)*ldb + k0 + aseg);
    __syncthreads();
    short8 a0 = *(const short8*)&As[mh + l16][quad*8];
    short8 a1 = *(const short8*)&As[mh + 16 + l16][quad*8];
    short8 b0 = *(const short8*)&Bs[nh + l16][quad*8];
    short8 b1 = *(const short8*)&Bs[nh + 16 + l16][quad*8];
    acc[0][0] = MFMA16(a0, b0, acc[0][0]);
    acc[0][1] = MFMA16(a0, b1, acc[0][1]);
    acc[1][0] = MFMA16(a1, b0, acc[1][0]);
    acc[1][1] = MFMA16(a1, b1, acc[1][1]);
    __syncthreads();
  }
  #pragma unroll
  for(int mi=0;mi<2;mi++){
    #pragma unroll
    for(int r=0;r<4;r++){
      int row = bm + mh + mi*16 + quad*4 + r;
      #pragma unroll
      for(int ni=0;ni<2;ni++){
        int col = bn + nh + ni*16 + l16;
        float v = acc[mi][ni][r];
        if(bias) v += bias[col];
        if(act==1) v = tanhf(v);
        if(act==2) ((ushort*)C)[(size_t)row*ldc + col] = f2bf(v);
        else       C[(size_t)row*ldc + col] = v;
      }
    }
  }
}

// ---------------- skewed persistent LSTM scan ----------------
// r4-proven lockstep architecture + skew (65 phases) + fan-in/fan-out barrier.
// This round: FENCE-FREE cross-block protocol. All cross-block data (h state,
// flags) moves via sc0+sc1 (agent-coherent, L2-bypassing) accesses:
//   - h stores were already sc1 (AST); the pre-s_barrier s_waitcnt vmcnt(0)
//     completes them at the coherence point, so the producer needs NO
//     __threadfence (no buffer_wbl2).
//   - h loads become explicit `global_load_dwordx4 ... sc0 sc1` inline asm
//     (wave-uniform base + imm offsets), so the consumer needs NO
//     __threadfence (no buffer_inv).
// Removes 32 L2-writebacks + 32 L2-invalidates per XCD per phase (the ~16
// us/phase serial floor; also the inv-induced HBM refetch seen in FETCH_SIZE).
// inp_bf/outstate stay plain stores: consumed only by later kernels
// (kernel-boundary flush). Release word replicated x16 (128B apart) to kill
// the 256-poller hot line; each block polls replica blk>>4.
__global__ __launch_bounds__(256,1) void lstm_skew(
    const ushort* __restrict__ Whh0b,   // [4096][1024] bf16
    const ushort* __restrict__ Wih1b,   // [4096][1024]
    const ushort* __restrict__ Whh1b,   // [4096][1024]
    const float*  __restrict__ G0,      // [T*32][4096] fp32 (bias0 folded)
    const float*  __restrict__ bias1c,  // [4096]
    const float*  __restrict__ c0in,    // [2][32][1024]
    ushort* __restrict__ hbuf,          // [4][32768]: h0p0,h0p1,h1p0,h1p1
    ushort* __restrict__ inp_bf,        // [T*32][1024]
    float*  __restrict__ outstate,      // h[2][32][1024] then c[2][32][1024]
    int* __restrict__ flags){           // [1024]: [0..255] arrivals, [512+32r] release replicas
  extern __shared__ char smem[];
  ushort (*W0s)[1032]   = (ushort(*)[1032])smem;                   // 33024 B
  ushort (*W1s)[2056]   = (ushort(*)[2056])(smem + 33024);         // 65792 B
  float (*gred0)[32][17] = (float(*)[32][17])(smem + 98816);       // 8704 B
  float (*gred1)[32][17] = (float(*)[32][17])(smem + 107520);      // 8704 B
  float (*cloc0)[4]      = (float(*)[4])(smem + 116224);           // 512 B
  float (*cloc1)[4]      = (float(*)[4])(smem + 116736);           // 512 B

  const int tid = threadIdx.x, w = tid>>6, lane = tid&63;
  const int quad = lane>>4, l16 = lane&15;
  const int blk = blockIdx.x;
  const int j0 = blk*4;

  // ---- load weight slices into LDS (held for all phases) — r4 verbatim ----
  {
    int r = tid>>4, seg = tid&15;                       // 16 rows x 16 segments
    int wr = (r>>2)*1024 + j0 + (r&3);                  // gate-major weight row
    const ushort* s0 = Whh0b + (size_t)wr*1024 + seg*64;
    const ushort* s1 = Wih1b + (size_t)wr*1024 + seg*64;
    const ushort* s2 = Whh1b + (size_t)wr*1024 + seg*64;
    #pragma unroll
    for(int u=0; u<64; u+=8){
      *(short8*)&W0s[r][seg*64+u]       = *(const short8*)(s0+u);
      *(short8*)&W1s[r][seg*64+u]       = *(const short8*)(s1+u);
      *(short8*)&W1s[r][1024+seg*64+u]  = *(const short8*)(s2+u);
    }
  }
  if(tid < 128){
    int b = tid>>2, jj = tid&3;
    cloc0[b][jj] = c0in[b*1024 + j0 + jj];
    cloc1[b][jj] = c0in[32768 + b*1024 + j0 + jj];
  }
  // loop-invariant bias1 in registers (layer-1 cell threads: tid 64..127)
  float2 pbI={0,0}, pbF={0,0}, pbG={0,0}, pbO={0,0};
  if(tid >= 64 && tid < 128){
    const float* br = bias1c + j0 + ((tid-64)&1)*2;
    pbI = *(const float2*)(br);
    pbF = *(const float2*)(br+1024);
    pbG = *(const float2*)(br+2048);
    pbO = *(const float2*)(br+3072);
  }
  __syncthreads();

  ushort* h0b[2] = { hbuf,            hbuf + 32768 };
  ushort* h1b[2] = { hbuf + 65536,    hbuf + 98304 };

  for(int p=0; p<=TDIM; p++){
    const int par = p&1, nxt = par^1;
    // G0 prefetch for layer0 step p (overlaps MFMA issue)
    float2 pgI={0,0}, pgF={0,0}, pgG={0,0}, pgO={0,0};
    if(p < TDIM && tid < 64){
      const float* g0r = G0 + (size_t)(p*32+(tid>>1))*4096 + j0 + (tid&1)*2;
      pgI = *(const float2*)(g0r);
      pgF = *(const float2*)(g0r+1024);
      pgG = *(const float2*)(g0r+2048);
      pgO = *(const float2*)(g0r+3072);
    }
    // ---- MFMA layer0 step p: gates0 = h0(p) @ W0s^T (K-split across waves) ----
    if(p < TDIM){
      f32x4 acc0 = {0,0,0,0}, acc1 = {0,0,0,0};
      const int kbase = w*256;
      // 16 coherent (sc0 sc1) 16B loads, wave-uniform base + imm offsets,
      // completed by the in-asm s_waitcnt before any use.
      short8 ha[8], hb[8];
      {
        const ushort* pa = h0b[par] + (size_t)l16*1024 + kbase + quad*8;
        const ushort* pb = pa + 16*1024;
        asm volatile(
          "global_load_dwordx4 %0, %16, off sc0 sc1\n\t"
          "global_load_dwordx4 %1, %16, off offset:64 sc0 sc1\n\t"
          "global_load_dwordx4 %2, %16, off offset:128 sc0 sc1\n\t"
          "global_load_dwordx4 %3, %16, off offset:192 sc0 sc1\n\t"
          "global_load_dwordx4 %4, %16, off offset:256 sc0 sc1\n\t"
          "global_load_dwordx4 %5, %16, off offset:320 sc0 sc1\n\t"
          "global_load_dwordx4 %6, %16, off offset:384 sc0 sc1\n\t"
          "global_load_dwordx4 %7, %16, off offset:448 sc0 sc1\n\t"
          "global_load_dwordx4 %8, %17, off sc0 sc1\n\t"
          "global_load_dwordx4 %9, %17, off offset:64 sc0 sc1\n\t"
          "global_load_dwordx4 %10, %17, off offset:128 sc0 sc1\n\t"
          "global_load_dwordx4 %11, %17, off offset:192 sc0 sc1\n\t"
          "global_load_dwordx4 %12, %17, off offset:256 sc0 sc1\n\t"
          "global_load_dwordx4 %13, %17, off offset:320 sc0 sc1\n\t"
          "global_load_dwordx4 %14, %17, off offset:384 sc0 sc1\n\t"
          "global_load_dwordx4 %15, %17, off offset:448 sc0 sc1\n\t"
          "s_waitcnt vmcnt(0)"
          : "=&v"(ha[0]), "=&v"(ha[1]), "=&v"(ha[2]), "=&v"(ha[3]),
            "=&v"(ha[4]), "=&v"(ha[5]), "=&v"(ha[6]), "=&v"(ha[7]),
            "=&v"(hb[0]), "=&v"(hb[1]), "=&v"(hb[2]), "=&v"(hb[3]),
            "=&v"(hb[4]), "=&v"(hb[5]), "=&v"(hb[6]), "=&v"(hb[7])
          : "v"(pa), "v"(pb)
          : "memory");
        __builtin_amdgcn_sched_barrier(0);
      }
      #pragma unroll
      for(int kc=0;kc<8;kc++){
        short8 bfrag = *(const short8*)&W0s[l16][kbase + kc*32 + quad*8];
        acc0 = MFMA16(ha[kc], bfrag, acc0);
        acc1 = MFMA16(hb[kc], bfrag, acc1);
      }
      #pragma unroll
      for(int r=0;r<4;r++){
        gred0[w][quad*4+r][l16]    = acc0[r];
        gred0[w][16+quad*4+r][l16] = acc1[r];
      }
    }
    // ---- MFMA layer1 step p-1: gates1 = [h0(p) | h1(p-1)] @ W1s^T ----
    // k = w*512 + kc*32 + quad*8: per-wave uniform buffer (w<2 -> h0, w>=2 -> h1)
    if(p > 0){
      f32x4 acc0 = {0,0,0,0}, acc1 = {0,0,0,0};
      short8 la[16], lb[16];
      {
        const ushort* base1 = (w < 2) ? h0b[par] : h1b[nxt];
        const ushort* pa = base1 + (size_t)l16*1024 + (w&1)*512 + quad*8;
        const ushort* pb = pa + 16*1024;
        asm volatile(
          "global_load_dwordx4 %0, %16, off sc0 sc1\n\t"
          "global_load_dwordx4 %1, %16, off offset:64 sc0 sc1\n\t"
          "global_load_dwordx4 %2, %16, off offset:128 sc0 sc1\n\t"
          "global_load_dwordx4 %3, %16, off offset:192 sc0 sc1\n\t"
          "global_load_dwordx4 %4, %16, off offset:256 sc0 sc1\n\t"
          "global_load_dwordx4 %5, %16, off offset:320 sc0 sc1\n\t"
          "global_load_dwordx4 %6, %16, off offset:384 sc0 sc1\n\t"
          "global_load_dwordx4 %7, %16, off offset:448 sc0 sc1\n\t"
          "global_load_dwordx4 %8, %16, off offset:512 sc0 sc1\n\t"
          "global_load_dwordx4 %9, %16, off offset:576 sc0 sc1\n\t"
          "global_load_dwordx4 %10, %16, off offset:640 sc0 sc1\n\t"
          "global_load_dwordx4 %11, %16, off offset:704 sc0 sc1\n\t"
          "global_load_dwordx4 %12, %16, off offset:768 sc0 sc1\n\t"
          "global_load_dwordx4 %13, %16, off offset:832 sc0 sc1\n\t"
          "global_load_dwordx4 %14, %16, off offset:896 sc0 sc1\n\t"
          "global_load_dwordx4 %15, %16, off offset:960 sc0 sc1"
          : "=&v"(la[0]), "=&v"(la[1]), "=&v"(la[2]), "=&v"(la[3]),
            "=&v"(la[4]), "=&v"(la[5]), "=&v"(la[6]), "=&v"(la[7]),
            "=&v"(la[8]), "=&v"(la[9]), "=&v"(la[10]), "=&v"(la[11]),
            "=&v"(la[12]), "=&v"(la[13]), "=&v"(la[14]), "=&v"(la[15])
          : "v"(pa)
          : "memory");
        asm volatile(
          "global_load_dwordx4 %0, %16, off sc0 sc1\n\t"
          "global_load_dwordx4 %1, %16, off offset:64 sc0 sc1\n\t"
          "global_load_dwordx4 %2, %16, off offset:128 sc0 sc1\n\t"
          "global_load_dwordx4 %3, %16, off offset:192 sc0 sc1\n\t"
          "global_load_dwordx4 %4, %16, off offset:256 sc0 sc1\n\t"
          "global_load_dwordx4 %5, %16, off offset:320 sc0 sc1\n\t"
          "global_load_dwordx4 %6, %16, off offset:384 sc0 sc1\n\t"
          "global_load_dwordx4 %7, %16, off offset:448 sc0 sc1\n\t"
          "global_load_dwordx4 %8, %16, off offset:512 sc0 sc1\n\t"
          "global_load_dwordx4 %9, %16, off offset:576 sc0 sc1\n\t"
          "global_load_dwordx4 %10, %16, off offset:640 sc0 sc1\n\t"
          "global_load_dwordx4 %11, %16, off offset:704 sc0 sc1\n\t"
          "global_load_dwordx4 %12, %16, off offset:768 sc0 sc1\n\t"
          "global_load_dwordx4 %13, %16, off offset:832 sc0 sc1\n\t"
          "global_load_dwordx4 %14, %16, off offset:896 sc0 sc1\n\t"
          "global_load_dwordx4 %15, %16, off offset:960 sc0 sc1\n\t"
          "s_waitcnt vmcnt(0)"
          : "=&v"(lb[0]), "=&v"(lb[1]), "=&v"(lb[2]), "=&v"(lb[3]),
            "=&v"(lb[4]), "=&v"(lb[5]), "=&v"(lb[6]), "=&v"(lb[7]),
            "=&v"(lb[8]), "=&v"(lb[9]), "=&v"(lb[10]), "=&v"(lb[11]),
            "=&v"(lb[12]), "=&v"(lb[13]), "=&v"(lb[14]), "=&v"(lb[15])
          : "v"(pb)
          : "memory");
        __builtin_amdgcn_sched_barrier(0);
      }
      #pragma unroll
      for(int kc=0;kc<16;kc++){
        short8 bfrag = *(const short8*)&W1s[l16][w*512 + kc*32 + quad*8];
        acc0 = MFMA16(la[kc], bfrag, acc0);
        acc1 = MFMA16(lb[kc], bfrag, acc1);
      }
      #pragma unroll
      for(int r=0;r<4;r++){
        gred1[w][quad*4+r][l16]    = acc0[r];
        gred1[w][16+quad*4+r][l16] = acc1[r];
      }
    }
    __syncthreads();
    // ---- layer0 cell (wave 0) ----
    if(p < TDIM && tid < 64){
      int b = tid>>1, j2 = (tid&1)*2;
      ushort hv[2];
      #pragma unroll
      for(int u=0;u<2;u++){
        int jj = j2+u;
        float gi = u ? pgI.y : pgI.x;
        float gf = u ? pgF.y : pgF.x;
        float gg = u ? pgG.y : pgG.x;
        float go = u ? pgO.y : pgO.x;
        #pragma unroll
        for(int ww=0;ww<4;ww++){
          gi += gred0[ww][b][jj];    gf += gred0[ww][b][4+jj];
          gg += gred0[ww][b][8+jj];  go += gred0[ww][b][12+jj];
        }
        float c = cloc0[b][jj];
        float c1 = sigm(gf)*c + sigm(gi)*tanhf(gg);
        float h1 = sigm(go)*tanhf(c1);
        cloc0[b][jj] = c1;
        hv[u] = f2bf(h1);
        if(p==TDIM-1){
          outstate[b*1024 + j0 + jj] = h1;          // hT layer0
          outstate[65536 + b*1024 + j0 + jj] = c1;  // cT layer0
        }
      }
      uint pk = (uint)hv[0] | ((uint)hv[1] << 16);
      AST((uint*)(h0b[nxt] + b*1024 + j0 + j2), pk);
    }
    // ---- layer1 cell (wave 1), step t = p-1 ----
    if(p > 0 && tid >= 64 && tid < 128){
      int ct = tid-64;
      int b = ct>>1, j2 = (ct&1)*2;
      ushort hv[2];
      #pragma unroll
      for(int u=0;u<2;u++){
        int jj = j2+u;
        float gi = u ? pbI.y : pbI.x;
        float gf = u ? pbF.y : pbF.x;
        float gg = u ? pbG.y : pbG.x;
        float go = u ? pbO.y : pbO.x;
        #pragma unroll
        for(int ww=0;ww<4;ww++){
          gi += gred1[ww][b][jj];    gf += gred1[ww][b][4+jj];
          gg += gred1[ww][b][8+jj];  go += gred1[ww][b][12+jj];
        }
        float c = cloc1[b][jj];
        float c1 = sigm(gf)*c + sigm(gi)*tanhf(gg);
        float h1 = sigm(go)*tanhf(c1);
        cloc1[b][jj] = c1;
        hv[u] = f2bf(h1);
        inp_bf[(size_t)((p-1)*32+b)*1024 + j0 + jj] = hv[u];
        if(p==TDIM){
          outstate[32768 + b*1024 + j0 + jj] = h1;          // hT layer1
          outstate[98304 + b*1024 + j0 + jj] = c1;          // cT layer1
        }
      }
      uint pk = (uint)hv[0] | ((uint)hv[1] << 16);
      AST((uint*)(h1b[par] + b*1024 + j0 + j2), pk);
    }
    if(p == TDIM) break;                 // last phase: kernel end flushes
    // ---- fence-free fan-in/fan-out barrier ----
    // __syncthreads: each wave's pre-barrier s_waitcnt vmcnt(0) completes its
    // sc1 h-stores at the coherence point -> arrival flag needs no wbl2.
    __syncthreads();
    const int target = p+1;
    if(tid==0) AST(&flags[blk], target);
    if(blk==0 && tid<64){
      // aggregator: 64 lanes, 4 coalesced consecutive-address loads/round
      while(true){
        int v0 = ALD(&flags[tid]);
        int v1 = ALD(&flags[tid+64]);
        int v2 = ALD(&flags[tid+128]);
        int v3 = ALD(&flags[tid+192]);
        int mn = min(min(v0,v1),min(v2,v3));
        if(__all(mn >= target)) break;
        __builtin_amdgcn_s_sleep(2);
      }
      if(tid<16) AST(&flags[512 + tid*32], target);  // 16 release replicas, 128B apart
    }
    if(tid==0){
      while(ALD(&flags[512 + (blk>>4)*32]) < target) __builtin_amdgcn_s_sleep(8);
    }
    __syncthreads();
  }
}

// ---------------- MFMA attention: block = (t-chunk of 16, b) ----------------
__global__ __launch_bounds__(256) void attn_mfma(
    const ushort* __restrict__ gamma_bf, // [2048][1024] rows t*32+b
    const ushort* __restrict__ ctxb,     // [32][64][1024] bf16
    const ushort* __restrict__ ctxT,     // [32][1024][64] bf16
    ushort* __restrict__ ctx_out){       // [2048][1024] bf16
  const int b = blockIdx.y, t0 = blockIdx.x*16;
  const int tid = threadIdx.x, w = tid>>6, lane = tid&63;
  const int quad = lane>>4, l16 = lane&15;
  __shared__ float S[16][68];
  __shared__ ushort Pb[16][72];
  {
    f32x4 acc = {0,0,0,0};
    const ushort* arow = gamma_bf + ((size_t)(t0+l16)*32 + b)*1024;
    const ushort* brow = ctxb + ((size_t)b*SDIM + w*16 + l16)*1024;
    #pragma unroll 8
    for(int kc=0;kc<32;kc++){
      short8 af = *(const short8*)(arow + kc*32 + quad*8);
      short8 bf = *(const short8*)(brow + kc*32 + quad*8);
      acc = MFMA16(af, bf, acc);
    }
    #pragma unroll
    for(int r=0;r<4;r++) S[quad*4+r][w*16+l16] = acc[r];
  }
  __syncthreads();
  if(tid < 16){
    float mx = -1e30f;
    for(int s=0;s<SDIM;s++) mx = fmaxf(mx, S[tid][s]);
    float sum = 0.f;
    for(int s=0;s<SDIM;s++) sum += expf(S[tid][s]-mx);
    float inv = 1.f/sum;
    for(int s=0;s<SDIM;s++) Pb[tid][s] = f2bf(expf(S[tid][s]-mx)*inv);
  }
  __syncthreads();
  const ushort* bbase = ctxT + ((size_t)b*HDIM + w*256)*SDIM;
  for(int nt=0; nt<16; nt++){
    f32x4 acc = {0,0,0,0};
    #pragma unroll
    for(int kc=0;kc<2;kc++){
      short8 af = *(const short8*)&Pb[l16][kc*32 + quad*8];
      short8 bf = *(const short8*)(bbase + (size_t)(nt*16+l16)*SDIM + kc*32 + quad*8);
      acc = MFMA16(af, bf, acc);
    }
    int n = w*256 + nt*16 + l16;
    #pragma unroll
    for(int r=0;r<4;r++){
      int t = t0 + quad*4 + r;
      ctx_out[((size_t)t*32 + b)*1024 + n] = f2bf(acc[r]);
    }
  }
}

extern "C" void kernel_launch(void* const* d_in, const int* in_sizes, int n_in,
                              void* d_out, int out_size, void* d_ws, size_t ws_size,
                              hipStream_t stream){
  const int*   tokens   = (const int*)  d_in[0];
  const float* h0       = (const float*)d_in[1];
  const float* c0       = (const float*)d_in[2];
  const float* contexts = (const float*)d_in[3];
  const float* emb      = (const float*)d_in[4];
  const float* W_ih     = (const float*)d_in[5];   // [2,4H,H]
  const float* W_hh     = (const float*)d_in[6];
  const float* b_ih     = (const float*)d_in[7];   // [2,4H]
  const float* b_hh     = (const float*)d_in[8];
  const float* W_in     = (const float*)d_in[9];   // [H,H]
  const float* b_in     = (const float*)d_in[10];
  const float* W_out    = (const float*)d_in[11];  // [H,2H]
  const float* b_out    = (const float*)d_in[12];

  float* out = (float*)d_out;
  const int TB = TDIM*BDIM;                        // 2048

  // ---- workspace layout ----
  char* wp = (char*)d_ws;
  float* G0      = (float*)wp;  wp += (size_t)TB*4*HDIM*4;          // 33.5 MB
  float* bias0c  = (float*)wp;  wp += 4096*4;
  float* bias1c  = (float*)wp;  wp += 4096*4;
  int*   flags   = (int*)wp;    wp += 4096;                         // 1024 ints
  ushort* X_bf   = (ushort*)wp; wp += (size_t)TB*HDIM*2;
  ushort* Wih0b  = (ushort*)wp; wp += (size_t)4*HDIM*HDIM*2;
  ushort* Whh0b  = (ushort*)wp; wp += (size_t)4*HDIM*HDIM*2;
  ushort* Wih1b  = (ushort*)wp; wp += (size_t)4*HDIM*HDIM*2;
  ushort* Whh1b  = (ushort*)wp; wp += (size_t)4*HDIM*HDIM*2;
  ushort* Winb   = (ushort*)wp; wp += (size_t)HDIM*HDIM*2;
  ushort* Woutb  = (ushort*)wp; wp += (size_t)HDIM*2*HDIM*2;
  ushort* inp_bf = (ushort*)wp; wp += (size_t)TB*HDIM*2;
  ushort* hbuf   = (ushort*)wp; wp += (size_t)4*BDIM*HDIM*2;
  ushort* ctxb_bf= (ushort*)wp; wp += (size_t)BDIM*SDIM*HDIM*2;
  ushort* ctxT_bf= (ushort*)wp; wp += (size_t)BDIM*SDIM*HDIM*2;
  ushort* gammaB = (ushort*)G0;                                     // overlay
  ushort* ctx_bf = X_bf;                                            // overlay

  // ---- prep ----
  init_state_kernel<<<256,256,0,stream>>>(h0, hbuf);
  bar_init_kernel<<<1,256,0,stream>>>(flags);
  cast_kernel<<<4096,256,0,stream>>>(W_ih,                       Wih0b, 4*HDIM*HDIM/4);
  cast_kernel<<<4096,256,0,stream>>>(W_hh,                       Whh0b, 4*HDIM*HDIM/4);
  cast_kernel<<<4096,256,0,stream>>>(W_ih + (size_t)4*HDIM*HDIM, Wih1b, 4*HDIM*HDIM/4);
  cast_kernel<<<4096,256,0,stream>>>(W_hh + (size_t)4*HDIM*HDIM, Whh1b, 4*HDIM*HDIM/4);
  cast_kernel<<<1024,256,0,stream>>>(W_in,  Winb,  HDIM*HDIM/4);
  cast_kernel<<<2048,256,0,stream>>>(W_out, Woutb, HDIM*2*HDIM/4);
  cast_kernel<<<2048,256,0,stream>>>(contexts, ctxb_bf, BDIM*SDIM*HDIM/4);
  transpose_ctx_kernel<<<dim3(16,32),256,0,stream>>>(contexts, ctxT_bf);
  bias_kernel<<<16,256,0,stream>>>(b_ih, b_hh, bias0c, bias1c);
  embed_kernel<<<TB,256,0,stream>>>(tokens, emb, X_bf);

  // ---- G0 = X @ Wih0^T + (b_ih0+b_hh0)  [2048,4096] fp32 ----
  gemm_mfma_bt<<<dim3(4*HDIM/64, TB/64),256,0,stream>>>(
      X_bf, X_bf, HDIM, HDIM, Wih0b, HDIM, bias0c, G0, 4*HDIM, HDIM, 0);

  // ---- skewed persistent scan (1 dispatch, 65 phases) ----
  lstm_skew<<<NBLK,256,117248,stream>>>(
      Whh0b, Wih1b, Whh1b, G0, bias1c, c0,
      hbuf, inp_bf, out + (size_t)TB*HDIM, flags);

  // ---- gamma = inp @ W_in^T + b_in -> bf16 (overlays G0) ----
  gemm_mfma_bt<<<dim3(HDIM/64, TB/64),256,0,stream>>>(
      inp_bf, inp_bf, HDIM, HDIM, Winb, HDIM, b_in, (float*)gammaB, HDIM, HDIM, 2);

  // ---- attention (MFMA) ----
  attn_mfma<<<dim3(4,32),256,0,stream>>>(gammaB, ctxb_bf, ctxT_bf, ctx_bf);

  // ---- out = tanh([ctx|inp] @ W_out^T + b_out) -> d_out ----
  gemm_mfma_bt<<<dim3(HDIM/64, TB/64),256,0,stream>>>(
      ctx_bf, inp_bf, HDIM, HDIM, Woutb, 2*HDIM, b_out, out, HDIM, 2*HDIM, 1);
}

// Round 4
// 930.216 us; speedup vs baseline: 1.9730x; 1.0813x over previous
//
#include <hip/hip_runtime.h>
#include <hip/hip_bf16.h>

#define HDIM 1024
#define BDIM 32
#define TDIM 64
#define SDIM 64
#define NBLK 256

typedef __attribute__((ext_vector_type(8))) short short8;
typedef __attribute__((ext_vector_type(4))) short s4v;
typedef __attribute__((ext_vector_type(4))) float f32x4;
typedef unsigned short ushort;
typedef unsigned int uint;

__device__ __forceinline__ float sigm(float x){ return 1.f/(1.f+expf(-x)); }
__device__ __forceinline__ ushort f2bf(float x){
  uint u = __float_as_uint(x);
  u = (u + 0x7FFF + ((u>>16)&1)) >> 16;   // RNE
  return (ushort)u;
}
#define MFMA16(a,b,c) __builtin_amdgcn_mfma_f32_16x16x32_bf16((a),(b),(c),0,0,0)
#define ALD(p)     __hip_atomic_load((p), __ATOMIC_RELAXED, __HIP_MEMORY_SCOPE_AGENT)
#define AST(p,v)   __hip_atomic_store((p),(v), __ATOMIC_RELAXED, __HIP_MEMORY_SCOPE_AGENT)

// h history layout (block-major, line-exclusive): state = [256 blocks][32 b][4 cols]
// ushort idx within a 32768-ushort state: blk*128 + b*4 + jj.
// Each block's 256B region shares no cache line with any other block -> any
// L2 store-allocation policy is safe; consumers' plain cached loads first-touch
// fresh addresses (rotating per-step buffers) so no stale L2/L1 line can exist.

// ---------------- init: bf16 h seeds into history slot 0 ----------------
__global__ void init_state_kernel(const float* __restrict__ h0,
                                  ushort* __restrict__ h0h,
                                  ushort* __restrict__ h1h){
  int i = blockIdx.x*256 + threadIdx.x;       // 0..65535
  int l = i >> 15, r = i & 32767;             // r = b*1024 + h
  int b = r >> 10, h = r & 1023;
  ushort* dst = l ? h1h : h0h;
  dst[(h>>2)*128 + b*4 + (h&3)] = f2bf(h0[i]);
}

__global__ void bar_init_kernel(int* flags){
  for(int i=threadIdx.x; i<1024; i+=256) flags[i] = 0;  // arrivals [0..255], release replicas [512..1023]
}

// ---------------- fp32 -> bf16 cast (vector x4) ----------------
__global__ void cast_kernel(const float* __restrict__ src, ushort* __restrict__ dst, int n4){
  int i = blockIdx.x*256 + threadIdx.x;
  if(i < n4){
    float4 v = ((const float4*)src)[i];
    ushort4 o; o.x=f2bf(v.x); o.y=f2bf(v.y); o.z=f2bf(v.z); o.w=f2bf(v.w);
    ((ushort4*)dst)[i] = o;
  }
}

// ---------------- contexts transpose: [32][64][1024] f32 -> [32][1024][64] bf16 ----
__global__ void transpose_ctx_kernel(const float* __restrict__ ctx, ushort* __restrict__ ctxT){
  int b = blockIdx.y;
  int n = blockIdx.x*64 + (threadIdx.x & 63);
  int s0 = (threadIdx.x >> 6) * 16;
  for(int s=s0; s<s0+16; s++){
    float v = ctx[((size_t)b*SDIM + s)*HDIM + n];
    ctxT[((size_t)b*HDIM + n)*SDIM + s] = f2bf(v);
  }
}

// ---------------- combined biases ----------------
__global__ void bias_kernel(const float* __restrict__ b_ih, const float* __restrict__ b_hh,
                            float* __restrict__ bias0, float* __restrict__ bias1){
  int i = blockIdx.x*256 + threadIdx.x;   // 0..4095
  bias0[i] = b_ih[i] + b_hh[i];
  bias1[i] = b_ih[4096+i] + b_hh[4096+i];
}

// ---------------- embedding gather + bf16 cast ----------------
__global__ void embed_kernel(const int* __restrict__ tokens,
                             const float* __restrict__ emb,
                             ushort* __restrict__ Xb){
  int tb = blockIdx.x;
  int tok = tokens[tb];
  const float4* src = (const float4*)(emb + (size_t)tok*HDIM);
  ushort4* dst = (ushort4*)(Xb + (size_t)tb*HDIM);
  float4 v = src[threadIdx.x];
  ushort4 o; o.x=f2bf(v.x); o.y=f2bf(v.y); o.z=f2bf(v.z); o.w=f2bf(v.w);
  dst[threadIdx.x] = o;
}

// ---------------- big MFMA GEMM: C = act(A@B^T + bias) ----------------
// act: 0 = fp32 store, 1 = tanh fp32 store, 2 = bf16 store
__global__ __launch_bounds__(256) void gemm_mfma_bt(
    const ushort* __restrict__ A0, const ushort* __restrict__ A1, int lda, int KSPLIT,
    const ushort* __restrict__ B, int ldb,
    const float* __restrict__ bias,
    float* __restrict__ C, int ldc, int K, int act){
  __shared__ ushort As[64][40];
  __shared__ ushort Bs[64][40];
  const int bm = blockIdx.y*64, bn = blockIdx.x*64;
  const int tid = threadIdx.x, w = tid>>6, lane = tid&63;
  const int quad = lane>>4, l16 = lane&15;
  const int mh = (w>>1)*32, nh = (w&1)*32;
  const int arow = tid>>2, aseg = (tid&3)*8;
  f32x4 acc[2][2];
  #pragma unroll
  for(int i=0;i<2;i++)
    #pragma unroll
    for(int j=0;j<2;j++) acc[i][j] = (f32x4){0.f,0.f,0.f,0.f};

  for(int k0=0;k0<K;k0+=32){
    int gk = k0 + aseg;
    const ushort* ap = (gk < KSPLIT) ? (A0 + (size_t)(bm+arow)*lda + gk)
                                     : (A1 + (size_t)(bm+arow)*lda + (gk - KSPLIT));
    *(float4*)&As[arow][aseg] = *(const float4*)ap;
    *(float4*)&Bs[arow][aseg] = *(const float4*)(B + (size_t)(bn+arow)*ldb + k0 + aseg);
    __syncthreads();
    short8 a0 = *(const short8*)&As[mh + l16][quad*8];
    short8 a1 = *(const short8*)&As[mh + 16 + l16][quad*8];
    short8 b0 = *(const short8*)&Bs[nh + l16][quad*8];
    short8 b1 = *(const short8*)&Bs[nh + 16 + l16][quad*8];
    acc[0][0] = MFMA16(a0, b0, acc[0][0]);
    acc[0][1] = MFMA16(a0, b1, acc[0][1]);
    acc[1][0] = MFMA16(a1, b0, acc[1][0]);
    acc[1][1] = MFMA16(a1, b1, acc[1][1]);
    __syncthreads();
  }
  #pragma unroll
  for(int mi=0;mi<2;mi++){
    #pragma unroll
    for(int r=0;r<4;r++){
      int row = bm + mh + mi*16 + quad*4 + r;
      #pragma unroll
      for(int ni=0;ni<2;ni++){
        int col = bn + nh + ni*16 + l16;
        float v = acc[mi][ni][r];
        if(bias) v += bias[col];
        if(act==1) v = tanhf(v);
        if(act==2) ((ushort*)C)[(size_t)row*ldc + col] = f2bf(v);
        else       C[(size_t)row*ldc + col] = v;
      }
    }
  }
}

// ---------------- skewed persistent LSTM scan ----------------
// r4 lockstep + skew (65 phases) + fence-free fan-in/fan-out barrier (r6).
// This round: CACHED h reads. h moves through rotating per-step buffers
// (h0_hist[t], h1_hist[t]) in a block-major line-exclusive layout. Producers
// keep sc1 write-through stores (drained by the pre-barrier vmcnt(0), proven
// r6); consumers use PLAIN cached loads — correct because each phase reads
// addresses never previously touched by any XCD (no stale L2/L1 copy can
// exist; L2 miss fills pull the fresh sc1 data from the coherence point).
// Kills the 48 MB/phase sc0sc1 L3-transaction storm (256x re-read of the
// same 2048 lines); each XCD now fetches h once and 31/32 blocks hit L2.
__global__ __launch_bounds__(256,1) void lstm_skew(
    const ushort* __restrict__ Whh0b,   // [4096][1024] bf16
    const ushort* __restrict__ Wih1b,   // [4096][1024]
    const ushort* __restrict__ Whh1b,   // [4096][1024]
    const float*  __restrict__ G0,      // [T*32][4096] fp32 (bias0 folded)
    const float*  __restrict__ bias1c,  // [4096]
    const float*  __restrict__ c0in,    // [2][32][1024]
    ushort* __restrict__ h0h,           // [65][32768] block-major h0 states
    ushort* __restrict__ h1h,           // [65][32768] block-major h1 states
    ushort* __restrict__ inp_bf,        // [T*32][1024]
    float*  __restrict__ outstate,      // h[2][32][1024] then c[2][32][1024]
    int* __restrict__ flags){           // [1024]: [0..255] arrivals, [512+32r] release replicas
  extern __shared__ char smem[];
  ushort (*W0s)[1032]   = (ushort(*)[1032])smem;                   // 33024 B
  ushort (*W1s)[2056]   = (ushort(*)[2056])(smem + 33024);         // 65792 B
  float (*gred0)[32][17] = (float(*)[32][17])(smem + 98816);       // 8704 B
  float (*gred1)[32][17] = (float(*)[32][17])(smem + 107520);      // 8704 B
  float (*cloc0)[4]      = (float(*)[4])(smem + 116224);           // 512 B
  float (*cloc1)[4]      = (float(*)[4])(smem + 116736);           // 512 B

  const int tid = threadIdx.x, w = tid>>6, lane = tid&63;
  const int quad = lane>>4, l16 = lane&15;
  const int blk = blockIdx.x;
  const int j0 = blk*4;

  // ---- load weight slices into LDS (held for all phases) — r4 verbatim ----
  {
    int r = tid>>4, seg = tid&15;                       // 16 rows x 16 segments
    int wr = (r>>2)*1024 + j0 + (r&3);                  // gate-major weight row
    const ushort* s0 = Whh0b + (size_t)wr*1024 + seg*64;
    const ushort* s1 = Wih1b + (size_t)wr*1024 + seg*64;
    const ushort* s2 = Whh1b + (size_t)wr*1024 + seg*64;
    #pragma unroll
    for(int u=0; u<64; u+=8){
      *(short8*)&W0s[r][seg*64+u]       = *(const short8*)(s0+u);
      *(short8*)&W1s[r][seg*64+u]       = *(const short8*)(s1+u);
      *(short8*)&W1s[r][1024+seg*64+u]  = *(const short8*)(s2+u);
    }
  }
  if(tid < 128){
    int b = tid>>2, jj = tid&3;
    cloc0[b][jj] = c0in[b*1024 + j0 + jj];
    cloc1[b][jj] = c0in[32768 + b*1024 + j0 + jj];
  }
  // loop-invariant bias1 in registers (layer-1 cell threads: tid 64..127)
  float2 pbI={0,0}, pbF={0,0}, pbG={0,0}, pbO={0,0};
  if(tid >= 64 && tid < 128){
    const float* br = bias1c + j0 + ((tid-64)&1)*2;
    pbI = *(const float2*)(br);
    pbF = *(const float2*)(br+1024);
    pbG = *(const float2*)(br+2048);
    pbO = *(const float2*)(br+3072);
  }
  __syncthreads();

  for(int p=0; p<=TDIM; p++){
    const ushort* h0p = h0h + (size_t)p*32768;        // h0 input state, step p
    ushort*       h0n = h0h + (size_t)(p+1)*32768;    // h0 output state
    const ushort* h1m = h1h + (size_t)(p>0?p-1:0)*32768; // h1 input state, step p-1
    ushort*       h1c = h1h + (size_t)p*32768;        // h1 output state
    // G0 prefetch for layer0 step p (overlaps MFMA issue)
    float2 pgI={0,0}, pgF={0,0}, pgG={0,0}, pgO={0,0};
    if(p < TDIM && tid < 64){
      const float* g0r = G0 + (size_t)(p*32+(tid>>1))*4096 + j0 + (tid&1)*2;
      pgI = *(const float2*)(g0r);
      pgF = *(const float2*)(g0r+1024);
      pgG = *(const float2*)(g0r+2048);
      pgO = *(const float2*)(g0r+3072);
    }
    // ---- MFMA layer0 step p: gates0 = h0(p) @ W0s^T (K-split across waves) ----
    if(p < TDIM){
      f32x4 acc0 = {0,0,0,0}, acc1 = {0,0,0,0};
      const int kbase = w*256;
      #pragma unroll
      for(int kc=0;kc<8;kc++){
        int k0 = kbase + kc*32 + quad*8;
        const ushort* pa = h0p + (k0>>2)*128 + l16*4;   // cols k0..k0+3 (this blk-region), row l16
        s4v a0lo = *(const s4v*)pa;
        s4v a0hi = *(const s4v*)(pa + 128);             // cols k0+4..k0+7 (next blk-region)
        s4v a1lo = *(const s4v*)(pa + 64);              // row l16+16
        s4v a1hi = *(const s4v*)(pa + 192);
        short8 af0 = __builtin_shufflevector(a0lo, a0hi, 0,1,2,3,4,5,6,7);
        short8 af1 = __builtin_shufflevector(a1lo, a1hi, 0,1,2,3,4,5,6,7);
        short8 bfrag = *(const short8*)&W0s[l16][k0];
        acc0 = MFMA16(af0, bfrag, acc0);
        acc1 = MFMA16(af1, bfrag, acc1);
      }
      #pragma unroll
      for(int r=0;r<4;r++){
        gred0[w][quad*4+r][l16]    = acc0[r];
        gred0[w][16+quad*4+r][l16] = acc1[r];
      }
    }
    // ---- MFMA layer1 step p-1: gates1 = [h0(p) | h1(p-1)] @ W1s^T ----
    // k = w*512 + kc*32 + quad*8: per-wave uniform buffer (w<2 -> h0, w>=2 -> h1)
    if(p > 0){
      f32x4 acc0 = {0,0,0,0}, acc1 = {0,0,0,0};
      const ushort* hb1 = (w < 2) ? h0p : h1m;
      const int kb = (w&1)*512;
      #pragma unroll
      for(int kc=0;kc<16;kc++){
        int k0 = kb + kc*32 + quad*8;
        const ushort* pa = hb1 + (k0>>2)*128 + l16*4;
        s4v a0lo = *(const s4v*)pa;
        s4v a0hi = *(const s4v*)(pa + 128);
        s4v a1lo = *(const s4v*)(pa + 64);
        s4v a1hi = *(const s4v*)(pa + 192);
        short8 af0 = __builtin_shufflevector(a0lo, a0hi, 0,1,2,3,4,5,6,7);
        short8 af1 = __builtin_shufflevector(a1lo, a1hi, 0,1,2,3,4,5,6,7);
        short8 bfrag = *(const short8*)&W1s[l16][w*512 + kc*32 + quad*8];
        acc0 = MFMA16(af0, bfrag, acc0);
        acc1 = MFMA16(af1, bfrag, acc1);
      }
      #pragma unroll
      for(int r=0;r<4;r++){
        gred1[w][quad*4+r][l16]    = acc0[r];
        gred1[w][16+quad*4+r][l16] = acc1[r];
      }
    }
    __syncthreads();
    // ---- layer0 cell (wave 0) ----
    if(p < TDIM && tid < 64){
      int b = tid>>1, j2 = (tid&1)*2;
      ushort hv[2];
      #pragma unroll
      for(int u=0;u<2;u++){
        int jj = j2+u;
        float gi = u ? pgI.y : pgI.x;
        float gf = u ? pgF.y : pgF.x;
        float gg = u ? pgG.y : pgG.x;
        float go = u ? pgO.y : pgO.x;
        #pragma unroll
        for(int ww=0;ww<4;ww++){
          gi += gred0[ww][b][jj];    gf += gred0[ww][b][4+jj];
          gg += gred0[ww][b][8+jj];  go += gred0[ww][b][12+jj];
        }
        float c = cloc0[b][jj];
        float c1 = sigm(gf)*c + sigm(gi)*tanhf(gg);
        float h1 = sigm(go)*tanhf(c1);
        cloc0[b][jj] = c1;
        hv[u] = f2bf(h1);
        if(p==TDIM-1){
          outstate[b*1024 + j0 + jj] = h1;          // hT layer0
          outstate[65536 + b*1024 + j0 + jj] = c1;  // cT layer0
        }
      }
      uint pk = (uint)hv[0] | ((uint)hv[1] << 16);
      AST((uint*)(h0n + blk*128 + b*4 + j2), pk);   // block-major, line-exclusive
    }
    // ---- layer1 cell (wave 1), step t = p-1 ----
    if(p > 0 && tid >= 64 && tid < 128){
      int ct = tid-64;
      int b = ct>>1, j2 = (ct&1)*2;
      ushort hv[2];
      #pragma unroll
      for(int u=0;u<2;u++){
        int jj = j2+u;
        float gi = u ? pbI.y : pbI.x;
        float gf = u ? pbF.y : pbF.x;
        float gg = u ? pbG.y : pbG.x;
        float go = u ? pbO.y : pbO.x;
        #pragma unroll
        for(int ww=0;ww<4;ww++){
          gi += gred1[ww][b][jj];    gf += gred1[ww][b][4+jj];
          gg += gred1[ww][b][8+jj];  go += gred1[ww][b][12+jj];
        }
        float c = cloc1[b][jj];
        float c1 = sigm(gf)*c + sigm(gi)*tanhf(gg);
        float h1 = sigm(go)*tanhf(c1);
        cloc1[b][jj] = c1;
        hv[u] = f2bf(h1);
        inp_bf[(size_t)((p-1)*32+b)*1024 + j0 + jj] = hv[u];
        if(p==TDIM){
          outstate[32768 + b*1024 + j0 + jj] = h1;          // hT layer1
          outstate[98304 + b*1024 + j0 + jj] = c1;          // cT layer1
        }
      }
      uint pk = (uint)hv[0] | ((uint)hv[1] << 16);
      AST((uint*)(h1c + blk*128 + b*4 + j2), pk);   // block-major, line-exclusive
    }
    if(p == TDIM) break;                 // last phase: kernel end flushes
    // ---- fence-free fan-in/fan-out barrier (r6-proven) ----
    __syncthreads();                     // per-wave vmcnt(0) drains sc1 h-stores
    const int target = p+1;
    if(tid==0) AST(&flags[blk], target);
    if(blk==0 && tid<64){
      // aggregator: 64 lanes, 4 coalesced consecutive-address loads/round
      while(true){
        int v0 = ALD(&flags[tid]);
        int v1 = ALD(&flags[tid+64]);
        int v2 = ALD(&flags[tid+128]);
        int v3 = ALD(&flags[tid+192]);
        int mn = min(min(v0,v1),min(v2,v3));
        if(__all(mn >= target)) break;
        __builtin_amdgcn_s_sleep(2);
      }
      if(tid<16) AST(&flags[512 + tid*32], target);  // 16 release replicas, 128B apart
    }
    if(tid==0){
      while(ALD(&flags[512 + (blk>>4)*32]) < target) __builtin_amdgcn_s_sleep(8);
    }
    __syncthreads();
  }
}

// ---------------- MFMA attention: block = (t-chunk of 16, b) ----------------
__global__ __launch_bounds__(256) void attn_mfma(
    const ushort* __restrict__ gamma_bf, // [2048][1024] rows t*32+b
    const ushort* __restrict__ ctxb,     // [32][64][1024] bf16
    const ushort* __restrict__ ctxT,     // [32][1024][64] bf16
    ushort* __restrict__ ctx_out){       // [2048][1024] bf16
  const int b = blockIdx.y, t0 = blockIdx.x*16;
  const int tid = threadIdx.x, w = tid>>6, lane = tid&63;
  const int quad = lane>>4, l16 = lane&15;
  __shared__ float S[16][68];
  __shared__ ushort Pb[16][72];
  {
    f32x4 acc = {0,0,0,0};
    const ushort* arow = gamma_bf + ((size_t)(t0+l16)*32 + b)*1024;
    const ushort* brow = ctxb + ((size_t)b*SDIM + w*16 + l16)*1024;
    #pragma unroll 8
    for(int kc=0;kc<32;kc++){
      short8 af = *(const short8*)(arow + kc*32 + quad*8);
      short8 bf = *(const short8*)(brow + kc*32 + quad*8);
      acc = MFMA16(af, bf, acc);
    }
    #pragma unroll
    for(int r=0;r<4;r++) S[quad*4+r][w*16+l16] = acc[r];
  }
  __syncthreads();
  if(tid < 16){
    float mx = -1e30f;
    for(int s=0;s<SDIM;s++) mx = fmaxf(mx, S[tid][s]);
    float sum = 0.f;
    for(int s=0;s<SDIM;s++) sum += expf(S[tid][s]-mx);
    float inv = 1.f/sum;
    for(int s=0;s<SDIM;s++) Pb[tid][s] = f2bf(expf(S[tid][s]-mx)*inv);
  }
  __syncthreads();
  const ushort* bbase = ctxT + ((size_t)b*HDIM + w*256)*SDIM;
  for(int nt=0; nt<16; nt++){
    f32x4 acc = {0,0,0,0};
    #pragma unroll
    for(int kc=0;kc<2;kc++){
      short8 af = *(const short8*)&Pb[l16][kc*32 + quad*8];
      short8 bf = *(const short8*)(bbase + (size_t)(nt*16+l16)*SDIM + kc*32 + quad*8);
      acc = MFMA16(af, bf, acc);
    }
    int n = w*256 + nt*16 + l16;
    #pragma unroll
    for(int r=0;r<4;r++){
      int t = t0 + quad*4 + r;
      ctx_out[((size_t)t*32 + b)*1024 + n] = f2bf(acc[r]);
    }
  }
}

extern "C" void kernel_launch(void* const* d_in, const int* in_sizes, int n_in,
                              void* d_out, int out_size, void* d_ws, size_t ws_size,
                              hipStream_t stream){
  const int*   tokens   = (const int*)  d_in[0];
  const float* h0       = (const float*)d_in[1];
  const float* c0       = (const float*)d_in[2];
  const float* contexts = (const float*)d_in[3];
  const float* emb      = (const float*)d_in[4];
  const float* W_ih     = (const float*)d_in[5];   // [2,4H,H]
  const float* W_hh     = (const float*)d_in[6];
  const float* b_ih     = (const float*)d_in[7];   // [2,4H]
  const float* b_hh     = (const float*)d_in[8];
  const float* W_in     = (const float*)d_in[9];   // [H,H]
  const float* b_in     = (const float*)d_in[10];
  const float* W_out    = (const float*)d_in[11];  // [H,2H]
  const float* b_out    = (const float*)d_in[12];

  float* out = (float*)d_out;
  const int TB = TDIM*BDIM;                        // 2048

  // ---- workspace layout ----
  char* wp = (char*)d_ws;
  float* G0      = (float*)wp;  wp += (size_t)TB*4*HDIM*4;          // 33.5 MB
  float* bias0c  = (float*)wp;  wp += 4096*4;
  float* bias1c  = (float*)wp;  wp += 4096*4;
  int*   flags   = (int*)wp;    wp += 4096;                         // 1024 ints
  ushort* X_bf   = (ushort*)wp; wp += (size_t)TB*HDIM*2;
  ushort* Wih0b  = (ushort*)wp; wp += (size_t)4*HDIM*HDIM*2;
  ushort* Whh0b  = (ushort*)wp; wp += (size_t)4*HDIM*HDIM*2;
  ushort* Wih1b  = (ushort*)wp; wp += (size_t)4*HDIM*HDIM*2;
  ushort* Whh1b  = (ushort*)wp; wp += (size_t)4*HDIM*HDIM*2;
  ushort* Winb   = (ushort*)wp; wp += (size_t)HDIM*HDIM*2;
  ushort* Woutb  = (ushort*)wp; wp += (size_t)HDIM*2*HDIM*2;
  ushort* inp_bf = (ushort*)wp; wp += (size_t)TB*HDIM*2;
  ushort* h0hist = (ushort*)wp; wp += (size_t)(TDIM+1)*BDIM*HDIM*2; // 65 x 64KB
  ushort* h1hist = (ushort*)wp; wp += (size_t)(TDIM+1)*BDIM*HDIM*2; // 65 x 64KB
  ushort* ctxb_bf= (ushort*)wp; wp += (size_t)BDIM*SDIM*HDIM*2;
  ushort* ctxT_bf= (ushort*)wp; wp += (size_t)BDIM*SDIM*HDIM*2;
  ushort* gammaB = (ushort*)G0;                                     // overlay
  ushort* ctx_bf = X_bf;                                            // overlay

  // ---- prep ----
  init_state_kernel<<<256,256,0,stream>>>(h0, h0hist, h1hist);
  bar_init_kernel<<<1,256,0,stream>>>(flags);
  cast_kernel<<<4096,256,0,stream>>>(W_ih,                       Wih0b, 4*HDIM*HDIM/4);
  cast_kernel<<<4096,256,0,stream>>>(W_hh,                       Whh0b, 4*HDIM*HDIM/4);
  cast_kernel<<<4096,256,0,stream>>>(W_ih + (size_t)4*HDIM*HDIM, Wih1b, 4*HDIM*HDIM/4);
  cast_kernel<<<4096,256,0,stream>>>(W_hh + (size_t)4*HDIM*HDIM, Whh1b, 4*HDIM*HDIM/4);
  cast_kernel<<<1024,256,0,stream>>>(W_in,  Winb,  HDIM*HDIM/4);
  cast_kernel<<<2048,256,0,stream>>>(W_out, Woutb, HDIM*2*HDIM/4);
  cast_kernel<<<2048,256,0,stream>>>(contexts, ctxb_bf, BDIM*SDIM*HDIM/4);
  transpose_ctx_kernel<<<dim3(16,32),256,0,stream>>>(contexts, ctxT_bf);
  bias_kernel<<<16,256,0,stream>>>(b_ih, b_hh, bias0c, bias1c);
  embed_kernel<<<TB,256,0,stream>>>(tokens, emb, X_bf);

  // ---- G0 = X @ Wih0^T + (b_ih0+b_hh0)  [2048,4096] fp32 ----
  gemm_mfma_bt<<<dim3(4*HDIM/64, TB/64),256,0,stream>>>(
      X_bf, X_bf, HDIM, HDIM, Wih0b, HDIM, bias0c, G0, 4*HDIM, HDIM, 0);

  // ---- skewed persistent scan (1 dispatch, 65 phases) ----
  lstm_skew<<<NBLK,256,117248,stream>>>(
      Whh0b, Wih1b, Whh1b, G0, bias1c, c0,
      h0hist, h1hist, inp_bf, out + (size_t)TB*HDIM, flags);

  // ---- gamma = inp @ W_in^T + b_in -> bf16 (overlays G0) ----
  gemm_mfma_bt<<<dim3(HDIM/64, TB/64),256,0,stream>>>(
      inp_bf, inp_bf, HDIM, HDIM, Winb, HDIM, b_in, (float*)gammaB, HDIM, HDIM, 2);

  // ---- attention (MFMA) ----
  attn_mfma<<<dim3(4,32),256,0,stream>>>(gammaB, ctxb_bf, ctxT_bf, ctx_bf);

  // ---- out = tanh([ctx|inp] @ W_out^T + b_out) -> d_out ----
  gemm_mfma_bt<<<dim3(HDIM/64, TB/64),256,0,stream>>>(
      ctx_bf, inp_bf, HDIM, HDIM, Woutb, 2*HDIM, b_out, out, HDIM, 2*HDIM, 1);
}

// Round 5
// 890.402 us; speedup vs baseline: 2.0612x; 1.0447x over previous
//
#include <hip/hip_runtime.h>
#include <hip/hip_bf16.h>

#define HDIM 1024
#define BDIM 32
#define TDIM 64
#define SDIM 64
#define NBLK 256

typedef __attribute__((ext_vector_type(8))) short short8;
typedef __attribute__((ext_vector_type(4))) short s4v;
typedef __attribute__((ext_vector_type(4))) float f32x4;
typedef unsigned short ushort;
typedef unsigned int uint;

__device__ __forceinline__ float sigm(float x){ return 1.f/(1.f+expf(-x)); }
__device__ __forceinline__ ushort f2bf(float x){
  uint u = __float_as_uint(x);
  u = (u + 0x7FFF + ((u>>16)&1)) >> 16;   // RNE
  return (ushort)u;
}
#define MFMA16(a,b,c) __builtin_amdgcn_mfma_f32_16x16x32_bf16((a),(b),(c),0,0,0)
#define ALD(p)     __hip_atomic_load((p), __ATOMIC_RELAXED, __HIP_MEMORY_SCOPE_AGENT)
#define AST(p,v)   __hip_atomic_store((p),(v), __ATOMIC_RELAXED, __HIP_MEMORY_SCOPE_AGENT)

// Batched h-fragment loader: 8 plain-cached 8B loads from one wave-uniform
// base + imm offsets (covers 2 K-chunks of the block-major h layout).
// All loads stay in flight; caller does ONE s_waitcnt vmcnt(0) +
// sched_barrier(0) before any use (rule: MFMA can hoist past asm waitcnt).
__device__ __forceinline__ void load8(const char* b, s4v* r){
  asm volatile(
    "global_load_dwordx2 %0, %8, off\n\t"
    "global_load_dwordx2 %1, %8, off offset:128\n\t"
    "global_load_dwordx2 %2, %8, off offset:256\n\t"
    "global_load_dwordx2 %3, %8, off offset:384\n\t"
    "global_load_dwordx2 %4, %8, off offset:2048\n\t"
    "global_load_dwordx2 %5, %8, off offset:2176\n\t"
    "global_load_dwordx2 %6, %8, off offset:2304\n\t"
    "global_load_dwordx2 %7, %8, off offset:2432\n\t"
    : "=&v"(r[0]), "=&v"(r[1]), "=&v"(r[2]), "=&v"(r[3]),
      "=&v"(r[4]), "=&v"(r[5]), "=&v"(r[6]), "=&v"(r[7])
    : "v"(b) : "memory");
}

// h history layout (block-major, line-exclusive): state = [256 blocks][32 b][4 cols]
// ushort idx within a 32768-ushort state: blk*128 + b*4 + jj.

// ---------------- init: bf16 h seeds into history slot 0 ----------------
__global__ void init_state_kernel(const float* __restrict__ h0,
                                  ushort* __restrict__ h0h,
                                  ushort* __restrict__ h1h){
  int i = blockIdx.x*256 + threadIdx.x;       // 0..65535
  int l = i >> 15, r = i & 32767;             // r = b*1024 + h
  int b = r >> 10, h = r & 1023;
  ushort* dst = l ? h1h : h0h;
  dst[(h>>2)*128 + b*4 + (h&3)] = f2bf(h0[i]);
}

__global__ void bar_init_kernel(int* flags){
  for(int i=threadIdx.x; i<1024; i+=256) flags[i] = 0;  // arrivals [0..511], release replicas [512..1023]
}

// ---------------- fp32 -> bf16 cast (vector x4) ----------------
__global__ void cast_kernel(const float* __restrict__ src, ushort* __restrict__ dst, int n4){
  int i = blockIdx.x*256 + threadIdx.x;
  if(i < n4){
    float4 v = ((const float4*)src)[i];
    ushort4 o; o.x=f2bf(v.x); o.y=f2bf(v.y); o.z=f2bf(v.z); o.w=f2bf(v.w);
    ((ushort4*)dst)[i] = o;
  }
}

// ---------------- contexts transpose: [32][64][1024] f32 -> [32][1024][64] bf16 ----
__global__ void transpose_ctx_kernel(const float* __restrict__ ctx, ushort* __restrict__ ctxT){
  int b = blockIdx.y;
  int n = blockIdx.x*64 + (threadIdx.x & 63);
  int s0 = (threadIdx.x >> 6) * 16;
  for(int s=s0; s<s0+16; s++){
    float v = ctx[((size_t)b*SDIM + s)*HDIM + n];
    ctxT[((size_t)b*HDIM + n)*SDIM + s] = f2bf(v);
  }
}

// ---------------- combined biases ----------------
__global__ void bias_kernel(const float* __restrict__ b_ih, const float* __restrict__ b_hh,
                            float* __restrict__ bias0, float* __restrict__ bias1){
  int i = blockIdx.x*256 + threadIdx.x;   // 0..4095
  bias0[i] = b_ih[i] + b_hh[i];
  bias1[i] = b_ih[4096+i] + b_hh[4096+i];
}

// ---------------- embedding gather + bf16 cast ----------------
__global__ void embed_kernel(const int* __restrict__ tokens,
                             const float* __restrict__ emb,
                             ushort* __restrict__ Xb){
  int tb = blockIdx.x;
  int tok = tokens[tb];
  const float4* src = (const float4*)(emb + (size_t)tok*HDIM);
  ushort4* dst = (ushort4*)(Xb + (size_t)tb*HDIM);
  float4 v = src[threadIdx.x];
  ushort4 o; o.x=f2bf(v.x); o.y=f2bf(v.y); o.z=f2bf(v.z); o.w=f2bf(v.w);
  dst[threadIdx.x] = o;
}

// ---------------- big MFMA GEMM: C = act(A@B^T + bias) ----------------
// act: 0 = fp32 store, 1 = tanh fp32 store, 2 = bf16 store
__global__ __launch_bounds__(256) void gemm_mfma_bt(
    const ushort* __restrict__ A0, const ushort* __restrict__ A1, int lda, int KSPLIT,
    const ushort* __restrict__ B, int ldb,
    const float* __restrict__ bias,
    float* __restrict__ C, int ldc, int K, int act){
  __shared__ ushort As[64][40];
  __shared__ ushort Bs[64][40];
  const int bm = blockIdx.y*64, bn = blockIdx.x*64;
  const int tid = threadIdx.x, w = tid>>6, lane = tid&63;
  const int quad = lane>>4, l16 = lane&15;
  const int mh = (w>>1)*32, nh = (w&1)*32;
  const int arow = tid>>2, aseg = (tid&3)*8;
  f32x4 acc[2][2];
  #pragma unroll
  for(int i=0;i<2;i++)
    #pragma unroll
    for(int j=0;j<2;j++) acc[i][j] = (f32x4){0.f,0.f,0.f,0.f};

  for(int k0=0;k0<K;k0+=32){
    int gk = k0 + aseg;
    const ushort* ap = (gk < KSPLIT) ? (A0 + (size_t)(bm+arow)*lda + gk)
                                     : (A1 + (size_t)(bm+arow)*lda + (gk - KSPLIT));
    *(float4*)&As[arow][aseg] = *(const float4*)ap;
    *(float4*)&Bs[arow][aseg] = *(const float4*)(B + (size_t)(bn+arow)*ldb + k0 + aseg);
    __syncthreads();
    short8 a0 = *(const short8*)&As[mh + l16][quad*8];
    short8 a1 = *(const short8*)&As[mh + 16 + l16][quad*8];
    short8 b0 = *(const short8*)&Bs[nh + l16][quad*8];
    short8 b1 = *(const short8*)&Bs[nh + 16 + l16][quad*8];
    acc[0][0] = MFMA16(a0, b0, acc[0][0]);
    acc[0][1] = MFMA16(a0, b1, acc[0][1]);
    acc[1][0] = MFMA16(a1, b0, acc[1][0]);
    acc[1][1] = MFMA16(a1, b1, acc[1][1]);
    __syncthreads();
  }
  #pragma unroll
  for(int mi=0;mi<2;mi++){
    #pragma unroll
    for(int r=0;r<4;r++){
      int row = bm + mh + mi*16 + quad*4 + r;
      #pragma unroll
      for(int ni=0;ni<2;ni++){
        int col = bn + nh + ni*16 + l16;
        float v = acc[mi][ni][r];
        if(bias) v += bias[col];
        if(act==1) v = tanhf(v);
        if(act==2) ((ushort*)C)[(size_t)row*ldc + col] = f2bf(v);
        else       C[(size_t)row*ldc + col] = v;
      }
    }
  }
}

// ---------------- skewed persistent LSTM scan ----------------
// r4 lockstep + skew (65 phases) + fence-free barrier (r6) + cached rotating
// h (r8). This round:
//  (a) Deterministic load batching: all 96 h-loads per wave issue up-front
//      via inline asm (wave-uniform base + imm offsets), ONE vmcnt(0), then
//      all MFMAs. Breaks the compiler's 60-VGPR just-in-time load schedule
//      (~24 exposed L2-latency waits/phase). VGPRs are free at 1 wave/SIMD.
//  (b) Slimmer barrier: per-WAVE arrival (waves 0/1 drain own vmcnt, post own
//      flag; 512 arrivals) kills the end-of-phase __syncthreads; gred is
//      parity double-buffered so no second __syncthreads is needed; every
//      wave self-gates on the release replica (uniform-address poll).
__global__ __launch_bounds__(256,1) void lstm_skew(
    const ushort* __restrict__ Whh0b,   // [4096][1024] bf16
    const ushort* __restrict__ Wih1b,   // [4096][1024]
    const ushort* __restrict__ Whh1b,   // [4096][1024]
    const float*  __restrict__ G0,      // [T*32][4096] fp32 (bias0 folded)
    const float*  __restrict__ bias1c,  // [4096]
    const float*  __restrict__ c0in,    // [2][32][1024]
    ushort* __restrict__ h0h,           // [65][32768] block-major h0 states
    ushort* __restrict__ h1h,           // [65][32768] block-major h1 states
    ushort* __restrict__ inp_bf,        // [T*32][1024]
    float*  __restrict__ outstate,      // h[2][32][1024] then c[2][32][1024]
    int* __restrict__ flags){           // [1024]: [0..511] arrivals (2/blk), [512+32r] release replicas
  extern __shared__ char smem[];
  ushort (*W0s)[1032]   = (ushort(*)[1032])smem;                   // 33024 B
  ushort (*W1s)[2056]   = (ushort(*)[2056])(smem + 33024);         // 65792 B
  typedef float gredT[4][32][17];                                  // 8704 B each
  gredT* gred0 = (gredT*)(smem + 98816);                           // [2] parity
  gredT* gred1 = (gredT*)(smem + 116224);                          // [2] parity
  float (*cloc0)[4]      = (float(*)[4])(smem + 133632);           // 512 B
  float (*cloc1)[4]      = (float(*)[4])(smem + 134144);           // 512 B

  const int tid = threadIdx.x, w = tid>>6, lane = tid&63;
  const int quad = lane>>4, l16 = lane&15;
  const int blk = blockIdx.x;
  const int j0 = blk*4;

  // ---- load weight slices into LDS (held for all phases) — r4 verbatim ----
  {
    int r = tid>>4, seg = tid&15;                       // 16 rows x 16 segments
    int wr = (r>>2)*1024 + j0 + (r&3);                  // gate-major weight row
    const ushort* s0 = Whh0b + (size_t)wr*1024 + seg*64;
    const ushort* s1 = Wih1b + (size_t)wr*1024 + seg*64;
    const ushort* s2 = Whh1b + (size_t)wr*1024 + seg*64;
    #pragma unroll
    for(int u=0; u<64; u+=8){
      *(short8*)&W0s[r][seg*64+u]       = *(const short8*)(s0+u);
      *(short8*)&W1s[r][seg*64+u]       = *(const short8*)(s1+u);
      *(short8*)&W1s[r][1024+seg*64+u]  = *(const short8*)(s2+u);
    }
  }
  if(tid < 128){
    int b = tid>>2, jj = tid&3;
    cloc0[b][jj] = c0in[b*1024 + j0 + jj];
    cloc1[b][jj] = c0in[32768 + b*1024 + j0 + jj];
  }
  // loop-invariant bias1 in registers (layer-1 cell threads: tid 64..127)
  float2 pbI={0,0}, pbF={0,0}, pbG={0,0}, pbO={0,0};
  if(tid >= 64 && tid < 128){
    const float* br = bias1c + j0 + ((tid-64)&1)*2;
    pbI = *(const float2*)(br);
    pbF = *(const float2*)(br+1024);
    pbG = *(const float2*)(br+2048);
    pbO = *(const float2*)(br+3072);
  }
  __syncthreads();

  for(int p=0; p<=TDIM; p++){
    const int par = p&1;
    const ushort* h0p = h0h + (size_t)p*32768;            // h0 input, step p
    ushort*       h0n = h0h + (size_t)(p+1)*32768;        // h0 output
    const ushort* h1m = h1h + (size_t)(p>0?p-1:0)*32768;  // h1 input, step p-1
    ushort*       h1c = h1h + (size_t)p*32768;            // h1 output

    // G0 prefetch for layer0 step p (plain loads; compiler waits at use)
    float2 pgI={0,0}, pgF={0,0}, pgG={0,0}, pgO={0,0};
    if(p < TDIM && tid < 64){
      const float* g0r = G0 + (size_t)(p*32+(tid>>1))*4096 + j0 + (tid&1)*2;
      pgI = *(const float2*)(g0r);
      pgF = *(const float2*)(g0r+1024);
      pgG = *(const float2*)(g0r+2048);
      pgO = *(const float2*)(g0r+3072);
    }

    // ---- issue ALL h loads up-front (96 x 8B per wave, all in flight) ----
    s4v r0[32]; s4v r1[64];
    if(p < TDIM){
      const char* b0 = (const char*)h0p + w*16384 + quad*512 + l16*8;
      load8(b0,        r0);
      load8(b0+4096,   r0+8);
      load8(b0+8192,   r0+16);
      load8(b0+12288,  r0+24);
    }
    if(p > 0){
      const char* b1 = (const char*)((w<2)?h0p:h1m) + (w&1)*32768 + quad*512 + l16*8;
      #pragma unroll
      for(int i=0;i<8;i++) load8(b1 + i*4096, r1 + i*8);
    }
    asm volatile("s_waitcnt vmcnt(0)" ::: "memory");
    __builtin_amdgcn_sched_barrier(0);

    // ---- MFMA layer0 step p: gates0 = h0(p) @ W0s^T (K-split across waves) ----
    if(p < TDIM){
      f32x4 acc0 = {0,0,0,0}, acc1 = {0,0,0,0};
      #pragma unroll
      for(int kc=0;kc<8;kc++){
        short8 af0 = __builtin_shufflevector(r0[kc*4+0], r0[kc*4+2], 0,1,2,3,4,5,6,7);
        short8 af1 = __builtin_shufflevector(r0[kc*4+1], r0[kc*4+3], 0,1,2,3,4,5,6,7);
        short8 bfrag = *(const short8*)&W0s[l16][w*256 + kc*32 + quad*8];
        acc0 = MFMA16(af0, bfrag, acc0);
        acc1 = MFMA16(af1, bfrag, acc1);
      }
      #pragma unroll
      for(int r=0;r<4;r++){
        gred0[par][w][quad*4+r][l16]    = acc0[r];
        gred0[par][w][16+quad*4+r][l16] = acc1[r];
      }
    }
    // ---- MFMA layer1 step p-1: gates1 = [h0(p) | h1(p-1)] @ W1s^T ----
    if(p > 0){
      f32x4 acc0 = {0,0,0,0}, acc1 = {0,0,0,0};
      #pragma unroll
      for(int kc=0;kc<16;kc++){
        short8 af0 = __builtin_shufflevector(r1[kc*4+0], r1[kc*4+2], 0,1,2,3,4,5,6,7);
        short8 af1 = __builtin_shufflevector(r1[kc*4+1], r1[kc*4+3], 0,1,2,3,4,5,6,7);
        short8 bfrag = *(const short8*)&W1s[l16][w*512 + kc*32 + quad*8];
        acc0 = MFMA16(af0, bfrag, acc0);
        acc1 = MFMA16(af1, bfrag, acc1);
      }
      #pragma unroll
      for(int r=0;r<4;r++){
        gred1[par][w][quad*4+r][l16]    = acc0[r];
        gred1[par][w][16+quad*4+r][l16] = acc1[r];
      }
    }
    __syncthreads();   // all waves' gred[par] visible to cell waves
    // ---- layer0 cell (wave 0) ----
    if(p < TDIM && tid < 64){
      int b = tid>>1, j2 = (tid&1)*2;
      ushort hv[2];
      #pragma unroll
      for(int u=0;u<2;u++){
        int jj = j2+u;
        float gi = u ? pgI.y : pgI.x;
        float gf = u ? pgF.y : pgF.x;
        float gg = u ? pgG.y : pgG.x;
        float go = u ? pgO.y : pgO.x;
        #pragma unroll
        for(int ww=0;ww<4;ww++){
          gi += gred0[par][ww][b][jj];    gf += gred0[par][ww][b][4+jj];
          gg += gred0[par][ww][b][8+jj];  go += gred0[par][ww][b][12+jj];
        }
        float c = cloc0[b][jj];
        float c1 = sigm(gf)*c + sigm(gi)*tanhf(gg);
        float h1 = sigm(go)*tanhf(c1);
        cloc0[b][jj] = c1;
        hv[u] = f2bf(h1);
        if(p==TDIM-1){
          outstate[b*1024 + j0 + jj] = h1;          // hT layer0
          outstate[65536 + b*1024 + j0 + jj] = c1;  // cT layer0
        }
      }
      uint pk = (uint)hv[0] | ((uint)hv[1] << 16);
      AST((uint*)(h0n + blk*128 + b*4 + j2), pk);   // block-major, line-exclusive
    }
    // ---- layer1 cell (wave 1), step t = p-1 ----
    if(p > 0 && tid >= 64 && tid < 128){
      int ct = tid-64;
      int b = ct>>1, j2 = (ct&1)*2;
      ushort hv[2];
      #pragma unroll
      for(int u=0;u<2;u++){
        int jj = j2+u;
        float gi = u ? pbI.y : pbI.x;
        float gf = u ? pbF.y : pbF.x;
        float gg = u ? pbG.y : pbG.x;
        float go = u ? pbO.y : pbO.x;
        #pragma unroll
        for(int ww=0;ww<4;ww++){
          gi += gred1[par][ww][b][jj];    gf += gred1[par][ww][b][4+jj];
          gg += gred1[par][ww][b][8+jj];  go += gred1[par][ww][b][12+jj];
        }
        float c = cloc1[b][jj];
        float c1 = sigm(gf)*c + sigm(gi)*tanhf(gg);
        float h1 = sigm(go)*tanhf(c1);
        cloc1[b][jj] = c1;
        hv[u] = f2bf(h1);
        inp_bf[(size_t)((p-1)*32+b)*1024 + j0 + jj] = hv[u];
        if(p==TDIM){
          outstate[32768 + b*1024 + j0 + jj] = h1;          // hT layer1
          outstate[98304 + b*1024 + j0 + jj] = c1;          // cT layer1
        }
      }
      uint pk = (uint)hv[0] | ((uint)hv[1] << 16);
      AST((uint*)(h1c + blk*128 + b*4 + j2), pk);   // block-major, line-exclusive
    }
    if(p == TDIM) break;                 // last phase: kernel end flushes

    // ---- per-wave arrival (waves 0,1 hold the cross-block h stores) ----
    const int target = p+1;
    if(tid < 128){
      asm volatile("s_waitcnt vmcnt(0)" ::: "memory");  // drain own sc1 h stores
      if((tid&63)==0) AST(&flags[blk*2 + w], target);
    }
    // ---- aggregator: block 0 wave 0 (after its own arrival) ----
    if(blk==0 && tid < 64){
      while(true){
        int mn = 0x7fffffff;
        #pragma unroll
        for(int q=0;q<8;q++){ int v = ALD(&flags[tid + q*64]); mn = min(mn, v); }
        if(__all(mn >= target)) break;
        __builtin_amdgcn_s_sleep(1);
      }
      if(tid < 16) AST(&flags[512 + tid*32], target);  // 16 release replicas
    }
    // ---- every wave self-gates on its release replica (uniform address) ----
    while(ALD(&flags[512 + (blk>>4)*32]) < target) __builtin_amdgcn_s_sleep(1);
    // no trailing __syncthreads: gred is parity double-buffered; intra-block
    // skew is bounded to <1 phase by the pre-cell __syncthreads above.
  }
}

// ---------------- MFMA attention: block = (t-chunk of 16, b) ----------------
__global__ __launch_bounds__(256) void attn_mfma(
    const ushort* __restrict__ gamma_bf, // [2048][1024] rows t*32+b
    const ushort* __restrict__ ctxb,     // [32][64][1024] bf16
    const ushort* __restrict__ ctxT,     // [32][1024][64] bf16
    ushort* __restrict__ ctx_out){       // [2048][1024] bf16
  const int b = blockIdx.y, t0 = blockIdx.x*16;
  const int tid = threadIdx.x, w = tid>>6, lane = tid&63;
  const int quad = lane>>4, l16 = lane&15;
  __shared__ float S[16][68];
  __shared__ ushort Pb[16][72];
  {
    f32x4 acc = {0,0,0,0};
    const ushort* arow = gamma_bf + ((size_t)(t0+l16)*32 + b)*1024;
    const ushort* brow = ctxb + ((size_t)b*SDIM + w*16 + l16)*1024;
    #pragma unroll 8
    for(int kc=0;kc<32;kc++){
      short8 af = *(const short8*)(arow + kc*32 + quad*8);
      short8 bf = *(const short8*)(brow + kc*32 + quad*8);
      acc = MFMA16(af, bf, acc);
    }
    #pragma unroll
    for(int r=0;r<4;r++) S[quad*4+r][w*16+l16] = acc[r];
  }
  __syncthreads();
  if(tid < 16){
    float mx = -1e30f;
    for(int s=0;s<SDIM;s++) mx = fmaxf(mx, S[tid][s]);
    float sum = 0.f;
    for(int s=0;s<SDIM;s++) sum += expf(S[tid][s]-mx);
    float inv = 1.f/sum;
    for(int s=0;s<SDIM;s++) Pb[tid][s] = f2bf(expf(S[tid][s]-mx)*inv);
  }
  __syncthreads();
  const ushort* bbase = ctxT + ((size_t)b*HDIM + w*256)*SDIM;
  for(int nt=0; nt<16; nt++){
    f32x4 acc = {0,0,0,0};
    #pragma unroll
    for(int kc=0;kc<2;kc++){
      short8 af = *(const short8*)&Pb[l16][kc*32 + quad*8];
      short8 bf = *(const short8*)(bbase + (size_t)(nt*16+l16)*SDIM + kc*32 + quad*8);
      acc = MFMA16(af, bf, acc);
    }
    int n = w*256 + nt*16 + l16;
    #pragma unroll
    for(int r=0;r<4;r++){
      int t = t0 + quad*4 + r;
      ctx_out[((size_t)t*32 + b)*1024 + n] = f2bf(acc[r]);
    }
  }
}

extern "C" void kernel_launch(void* const* d_in, const int* in_sizes, int n_in,
                              void* d_out, int out_size, void* d_ws, size_t ws_size,
                              hipStream_t stream){
  const int*   tokens   = (const int*)  d_in[0];
  const float* h0       = (const float*)d_in[1];
  const float* c0       = (const float*)d_in[2];
  const float* contexts = (const float*)d_in[3];
  const float* emb      = (const float*)d_in[4];
  const float* W_ih     = (const float*)d_in[5];   // [2,4H,H]
  const float* W_hh     = (const float*)d_in[6];
  const float* b_ih     = (const float*)d_in[7];   // [2,4H]
  const float* b_hh     = (const float*)d_in[8];
  const float* W_in     = (const float*)d_in[9];   // [H,H]
  const float* b_in     = (const float*)d_in[10];
  const float* W_out    = (const float*)d_in[11];  // [H,2H]
  const float* b_out    = (const float*)d_in[12];

  float* out = (float*)d_out;
  const int TB = TDIM*BDIM;                        // 2048

  // ---- workspace layout ----
  char* wp = (char*)d_ws;
  float* G0      = (float*)wp;  wp += (size_t)TB*4*HDIM*4;          // 33.5 MB
  float* bias0c  = (float*)wp;  wp += 4096*4;
  float* bias1c  = (float*)wp;  wp += 4096*4;
  int*   flags   = (int*)wp;    wp += 4096;                         // 1024 ints
  ushort* X_bf   = (ushort*)wp; wp += (size_t)TB*HDIM*2;
  ushort* Wih0b  = (ushort*)wp; wp += (size_t)4*HDIM*HDIM*2;
  ushort* Whh0b  = (ushort*)wp; wp += (size_t)4*HDIM*HDIM*2;
  ushort* Wih1b  = (ushort*)wp; wp += (size_t)4*HDIM*HDIM*2;
  ushort* Whh1b  = (ushort*)wp; wp += (size_t)4*HDIM*HDIM*2;
  ushort* Winb   = (ushort*)wp; wp += (size_t)HDIM*HDIM*2;
  ushort* Woutb  = (ushort*)wp; wp += (size_t)HDIM*2*HDIM*2;
  ushort* inp_bf = (ushort*)wp; wp += (size_t)TB*HDIM*2;
  ushort* h0hist = (ushort*)wp; wp += (size_t)(TDIM+1)*BDIM*HDIM*2; // 65 x 64KB
  ushort* h1hist = (ushort*)wp; wp += (size_t)(TDIM+1)*BDIM*HDIM*2; // 65 x 64KB
  ushort* ctxb_bf= (ushort*)wp; wp += (size_t)BDIM*SDIM*HDIM*2;
  ushort* ctxT_bf= (ushort*)wp; wp += (size_t)BDIM*SDIM*HDIM*2;
  ushort* gammaB = (ushort*)G0;                                     // overlay
  ushort* ctx_bf = X_bf;                                            // overlay

  // ---- prep ----
  init_state_kernel<<<256,256,0,stream>>>(h0, h0hist, h1hist);
  bar_init_kernel<<<1,256,0,stream>>>(flags);
  cast_kernel<<<4096,256,0,stream>>>(W_ih,                       Wih0b, 4*HDIM*HDIM/4);
  cast_kernel<<<4096,256,0,stream>>>(W_hh,                       Whh0b, 4*HDIM*HDIM/4);
  cast_kernel<<<4096,256,0,stream>>>(W_ih + (size_t)4*HDIM*HDIM, Wih1b, 4*HDIM*HDIM/4);
  cast_kernel<<<4096,256,0,stream>>>(W_hh + (size_t)4*HDIM*HDIM, Whh1b, 4*HDIM*HDIM/4);
  cast_kernel<<<1024,256,0,stream>>>(W_in,  Winb,  HDIM*HDIM/4);
  cast_kernel<<<2048,256,0,stream>>>(W_out, Woutb, HDIM*2*HDIM/4);
  cast_kernel<<<2048,256,0,stream>>>(contexts, ctxb_bf, BDIM*SDIM*HDIM/4);
  transpose_ctx_kernel<<<dim3(16,32),256,0,stream>>>(contexts, ctxT_bf);
  bias_kernel<<<16,256,0,stream>>>(b_ih, b_hh, bias0c, bias1c);
  embed_kernel<<<TB,256,0,stream>>>(tokens, emb, X_bf);

  // ---- G0 = X @ Wih0^T + (b_ih0+b_hh0)  [2048,4096] fp32 ----
  gemm_mfma_bt<<<dim3(4*HDIM/64, TB/64),256,0,stream>>>(
      X_bf, X_bf, HDIM, HDIM, Wih0b, HDIM, bias0c, G0, 4*HDIM, HDIM, 0);

  // ---- skewed persistent scan (1 dispatch, 65 phases) ----
  lstm_skew<<<NBLK,256,134656,stream>>>(
      Whh0b, Wih1b, Whh1b, G0, bias1c, c0,
      h0hist, h1hist, inp_bf, out + (size_t)TB*HDIM, flags);

  // ---- gamma = inp @ W_in^T + b_in -> bf16 (overlays G0) ----
  gemm_mfma_bt<<<dim3(HDIM/64, TB/64),256,0,stream>>>(
      inp_bf, inp_bf, HDIM, HDIM, Winb, HDIM, b_in, (float*)gammaB, HDIM, HDIM, 2);

  // ---- attention (MFMA) ----
  attn_mfma<<<dim3(4,32),256,0,stream>>>(gammaB, ctxb_bf, ctxT_bf, ctx_bf);

  // ---- out = tanh([ctx|inp] @ W_out^T + b_out) -> d_out ----
  gemm_mfma_bt<<<dim3(HDIM/64, TB/64),256,0,stream>>>(
      ctx_bf, inp_bf, HDIM, HDIM, Woutb, 2*HDIM, b_out, out, HDIM, 2*HDIM, 1);
}

// Round 6
// 820.079 us; speedup vs baseline: 2.2380x; 1.0858x over previous
//
#include <hip/hip_runtime.h>
#include <hip/hip_bf16.h>

#define HDIM 1024
#define BDIM 32
#define TDIM 64
#define SDIM 64
#define NBLK 256

typedef __attribute__((ext_vector_type(8))) short short8;
typedef __attribute__((ext_vector_type(4))) short s4v;
typedef __attribute__((ext_vector_type(4))) float f32x4;
typedef __attribute__((ext_vector_type(2))) float f32x2;
typedef unsigned short ushort;
typedef unsigned int uint;

__device__ __forceinline__ float sigm(float x){ return 1.f/(1.f+expf(-x)); }
__device__ __forceinline__ ushort f2bf(float x){
  uint u = __float_as_uint(x);
  u = (u + 0x7FFF + ((u>>16)&1)) >> 16;   // RNE
  return (ushort)u;
}
#define MFMA16(a,b,c) __builtin_amdgcn_mfma_f32_16x16x32_bf16((a),(b),(c),0,0,0)
#define ALD(p)     __hip_atomic_load((p), __ATOMIC_RELAXED, __HIP_MEMORY_SCOPE_AGENT)
#define AST(p,v)   __hip_atomic_store((p),(v), __ATOMIC_RELAXED, __HIP_MEMORY_SCOPE_AGENT)

// Batched h-fragment loader: 8 plain-cached 8B loads from one wave-uniform
// base + imm offsets. Loads stay in flight; caller inserts the s_waitcnt +
// sched_barrier(0) (rule #18) before consumption.
__device__ __forceinline__ void load8(const char* b, s4v* r){
  asm volatile(
    "global_load_dwordx2 %0, %8, off\n\t"
    "global_load_dwordx2 %1, %8, off offset:128\n\t"
    "global_load_dwordx2 %2, %8, off offset:256\n\t"
    "global_load_dwordx2 %3, %8, off offset:384\n\t"
    "global_load_dwordx2 %4, %8, off offset:2048\n\t"
    "global_load_dwordx2 %5, %8, off offset:2176\n\t"
    "global_load_dwordx2 %6, %8, off offset:2304\n\t"
    "global_load_dwordx2 %7, %8, off offset:2432\n\t"
    : "=&v"(r[0]), "=&v"(r[1]), "=&v"(r[2]), "=&v"(r[3]),
      "=&v"(r[4]), "=&v"(r[5]), "=&v"(r[6]), "=&v"(r[7])
    : "v"(b) : "memory");
}

// h history layout (block-major, line-exclusive): state = [256 blocks][32 b][4 cols]
// ushort idx within a 32768-ushort state: blk*128 + b*4 + jj.

// ---------------- init: bf16 h seeds into history slot 0 ----------------
__global__ void init_state_kernel(const float* __restrict__ h0,
                                  ushort* __restrict__ h0h,
                                  ushort* __restrict__ h1h){
  int i = blockIdx.x*256 + threadIdx.x;       // 0..65535
  int l = i >> 15, r = i & 32767;             // r = b*1024 + h
  int b = r >> 10, h = r & 1023;
  ushort* dst = l ? h1h : h0h;
  dst[(h>>2)*128 + b*4 + (h&3)] = f2bf(h0[i]);
}

__global__ void bar_init_kernel(int* flags){
  for(int i=threadIdx.x; i<1024; i+=256) flags[i] = 0;  // arrivals [0..511], release replicas [512..1023]
}

// ---------------- fused fp32 -> bf16 cast: all 7 segments, one launch ----------------
// prefix sums (float4 units): Wih0 1048576 | Whh0 1048576 | Wih1 1048576 |
// Whh1 1048576 | Win 262144 | Wout 524288 | ctx 524288  => total 5505024 = 21504*256
__global__ void fused_cast_kernel(
    const float* __restrict__ W_ih, const float* __restrict__ W_hh,
    const float* __restrict__ W_in, const float* __restrict__ W_out,
    const float* __restrict__ ctx,
    ushort* __restrict__ Wih0b, ushort* __restrict__ Whh0b,
    ushort* __restrict__ Wih1b, ushort* __restrict__ Whh1b,
    ushort* __restrict__ Winb,  ushort* __restrict__ Woutb,
    ushort* __restrict__ ctxb){
  long i = (long)blockIdx.x*256 + threadIdx.x;
  const float* src; ushort* dst; long off;
  if(i < 2097152){
    if(i < 1048576){ src=W_ih;          dst=Wih0b; off=i; }
    else           { src=W_hh;          dst=Whh0b; off=i-1048576; }
  } else if(i < 4194304){
    if(i < 3145728){ src=W_ih+4194304;  dst=Wih1b; off=i-2097152; }
    else           { src=W_hh+4194304;  dst=Whh1b; off=i-3145728; }
  } else if(i < 4456448){ src=W_in;     dst=Winb;  off=i-4194304; }
  else if(i < 4980736){   src=W_out;    dst=Woutb; off=i-4456448; }
  else {                  src=ctx;      dst=ctxb;  off=i-4980736; }
  float4 v = ((const float4*)src)[off];
  ushort4 o; o.x=f2bf(v.x); o.y=f2bf(v.y); o.z=f2bf(v.z); o.w=f2bf(v.w);
  ((ushort4*)dst)[off] = o;
}

// ---------------- contexts transpose: [32][64][1024] f32 -> [32][1024][64] bf16 ----
__global__ void transpose_ctx_kernel(const float* __restrict__ ctx, ushort* __restrict__ ctxT){
  int b = blockIdx.y;
  int n = blockIdx.x*64 + (threadIdx.x & 63);
  int s0 = (threadIdx.x >> 6) * 16;
  for(int s=s0; s<s0+16; s++){
    float v = ctx[((size_t)b*SDIM + s)*HDIM + n];
    ctxT[((size_t)b*HDIM + n)*SDIM + s] = f2bf(v);
  }
}

// ---------------- combined biases ----------------
__global__ void bias_kernel(const float* __restrict__ b_ih, const float* __restrict__ b_hh,
                            float* __restrict__ bias0, float* __restrict__ bias1){
  int i = blockIdx.x*256 + threadIdx.x;   // 0..4095
  bias0[i] = b_ih[i] + b_hh[i];
  bias1[i] = b_ih[4096+i] + b_hh[4096+i];
}

// ---------------- embedding gather + bf16 cast ----------------
__global__ void embed_kernel(const int* __restrict__ tokens,
                             const float* __restrict__ emb,
                             ushort* __restrict__ Xb){
  int tb = blockIdx.x;
  int tok = tokens[tb];
  const float4* src = (const float4*)(emb + (size_t)tok*HDIM);
  ushort4* dst = (ushort4*)(Xb + (size_t)tb*HDIM);
  float4 v = src[threadIdx.x];
  ushort4 o; o.x=f2bf(v.x); o.y=f2bf(v.y); o.z=f2bf(v.z); o.w=f2bf(v.w);
  dst[threadIdx.x] = o;
}

// ---------------- big MFMA GEMM: C = act(A@B^T + bias) ----------------
// act: 0 = fp32 store, 1 = tanh fp32 store, 2 = bf16 store
__global__ __launch_bounds__(256) void gemm_mfma_bt(
    const ushort* __restrict__ A0, const ushort* __restrict__ A1, int lda, int KSPLIT,
    const ushort* __restrict__ B, int ldb,
    const float* __restrict__ bias,
    float* __restrict__ C, int ldc, int K, int act){
  __shared__ ushort As[64][40];
  __shared__ ushort Bs[64][40];
  const int bm = blockIdx.y*64, bn = blockIdx.x*64;
  const int tid = threadIdx.x, w = tid>>6, lane = tid&63;
  const int quad = lane>>4, l16 = lane&15;
  const int mh = (w>>1)*32, nh = (w&1)*32;
  const int arow = tid>>2, aseg = (tid&3)*8;
  f32x4 acc[2][2];
  #pragma unroll
  for(int i=0;i<2;i++)
    #pragma unroll
    for(int j=0;j<2;j++) acc[i][j] = (f32x4){0.f,0.f,0.f,0.f};

  for(int k0=0;k0<K;k0+=32){
    int gk = k0 + aseg;
    const ushort* ap = (gk < KSPLIT) ? (A0 + (size_t)(bm+arow)*lda + gk)
                                     : (A1 + (size_t)(bm+arow)*lda + (gk - KSPLIT));
    *(float4*)&As[arow][aseg] = *(const float4*)ap;
    *(float4*)&Bs[arow][aseg] = *(const float4*)(B + (size_t)(bn+arow)*ldb + k0 + aseg);
    __syncthreads();
    short8 a0 = *(const short8*)&As[mh + l16][quad*8];
    short8 a1 = *(const short8*)&As[mh + 16 + l16][quad*8];
    short8 b0 = *(const short8*)&Bs[nh + l16][quad*8];
    short8 b1 = *(const short8*)&Bs[nh + 16 + l16][quad*8];
    acc[0][0] = MFMA16(a0, b0, acc[0][0]);
    acc[0][1] = MFMA16(a0, b1, acc[0][1]);
    acc[1][0] = MFMA16(a1, b0, acc[1][0]);
    acc[1][1] = MFMA16(a1, b1, acc[1][1]);
    __syncthreads();
  }
  #pragma unroll
  for(int mi=0;mi<2;mi++){
    #pragma unroll
    for(int r=0;r<4;r++){
      int row = bm + mh + mi*16 + quad*4 + r;
      #pragma unroll
      for(int ni=0;ni<2;ni++){
        int col = bn + nh + ni*16 + l16;
        float v = acc[mi][ni][r];
        if(bias) v += bias[col];
        if(act==1) v = tanhf(v);
        if(act==2) ((ushort*)C)[(size_t)row*ldc + col] = f2bf(v);
        else       C[(size_t)row*ldc + col] = v;
      }
    }
  }
}

// ---------------- skewed persistent LSTM scan (skew-2) ----------------
// Phase p (p=0..TDIM+1): L0 step p (p<TDIM), L1 step p-2 (p>=2).
// PRE-barrier: L1's x-half (h0h[p-1], written 2 phases back, gated by the
// PREVIOUS release -> race-free) loads+MFMAs run BEFORE the release poll,
// hiding them under the exchange latency. L2-warm (same XCD read those lines
// last phase). G0 prefetch via asm keeps vmcnt deterministic.
// POST-barrier: L0 (h0h[p], new) + L1's h1-half (h1h[p-2], new) with counted
// vmcnt(32): L0's 32 loads complete first, L0 MFMAs overlap L1h1 tail.
// Registers stage naturally: PRE 64 VGPR consumed before POST's 128 pinned
// (fixes r5's pressure collapse). Barrier: fence-free fan-in/fan-out (r6),
// per-wave arrivals, 16 release replicas.
__global__ __launch_bounds__(256,1) void lstm_skew(
    const ushort* __restrict__ Whh0b,   // [4096][1024] bf16
    const ushort* __restrict__ Wih1b,   // [4096][1024]
    const ushort* __restrict__ Whh1b,   // [4096][1024]
    const float*  __restrict__ G0,      // [T*32][4096] fp32 (bias0 folded)
    const float*  __restrict__ bias1c,  // [4096]
    const float*  __restrict__ c0in,    // [2][32][1024]
    ushort* __restrict__ h0h,           // [66][32768] block-major h0 states
    ushort* __restrict__ h1h,           // [65][32768] block-major h1 states
    ushort* __restrict__ inp_bf,        // [T*32][1024]
    float*  __restrict__ outstate,      // h[2][32][1024] then c[2][32][1024]
    int* __restrict__ flags){           // [1024]: [0..511] arrivals (2/blk), [512+32r] release replicas
  extern __shared__ char smem[];
  ushort (*W0s)[1032]   = (ushort(*)[1032])smem;                   // 33024 B
  ushort (*W1s)[2056]   = (ushort(*)[2056])(smem + 33024);         // 65792 B
  typedef float gredT[4][32][17];                                  // 8704 B each
  gredT* gred0 = (gredT*)(smem + 98816);                           // [2] parity
  gredT* gred1 = (gredT*)(smem + 116224);                          // [2] parity
  float (*cloc0)[4]      = (float(*)[4])(smem + 133632);           // 512 B
  float (*cloc1)[4]      = (float(*)[4])(smem + 134144);           // 512 B

  const int tid = threadIdx.x, w = tid>>6, lane = tid&63;
  const int quad = lane>>4, l16 = lane&15;
  const int blk = blockIdx.x;
  const int j0 = blk*4;

  // ---- load weight slices into LDS (held for all phases) — r4 verbatim ----
  {
    int r = tid>>4, seg = tid&15;                       // 16 rows x 16 segments
    int wr = (r>>2)*1024 + j0 + (r&3);                  // gate-major weight row
    const ushort* s0 = Whh0b + (size_t)wr*1024 + seg*64;
    const ushort* s1 = Wih1b + (size_t)wr*1024 + seg*64;
    const ushort* s2 = Whh1b + (size_t)wr*1024 + seg*64;
    #pragma unroll
    for(int u=0; u<64; u+=8){
      *(short8*)&W0s[r][seg*64+u]       = *(const short8*)(s0+u);
      *(short8*)&W1s[r][seg*64+u]       = *(const short8*)(s1+u);
      *(short8*)&W1s[r][1024+seg*64+u]  = *(const short8*)(s2+u);
    }
  }
  if(tid < 128){
    int b = tid>>2, jj = tid&3;
    cloc0[b][jj] = c0in[b*1024 + j0 + jj];
    cloc1[b][jj] = c0in[32768 + b*1024 + j0 + jj];
  }
  // loop-invariant bias1 in registers (layer-1 cell threads: tid 64..127)
  float2 pbI={0,0}, pbF={0,0}, pbG={0,0}, pbO={0,0};
  if(tid >= 64 && tid < 128){
    const float* br = bias1c + j0 + ((tid-64)&1)*2;
    pbI = *(const float2*)(br);
    pbF = *(const float2*)(br+1024);
    pbG = *(const float2*)(br+2048);
    pbO = *(const float2*)(br+3072);
  }
  __syncthreads();

  for(int p=0; p<=TDIM+1; p++){
    const int par = p&1;
    const bool doL0 = (p < TDIM);
    const bool doL1 = (p >= 2);
    const ushort* h0p    = h0h + (size_t)p*32768;             // L0 input (POST)
    ushort*       h0n    = h0h + (size_t)(p+1)*32768;         // L0 output
    const ushort* h0prev = h0h + (size_t)(p>=1?p-1:0)*32768;  // L1 x-input (PRE)
    const ushort* h1m    = h1h + (size_t)(p>=2?p-2:0)*32768;  // L1 state input (POST)
    ushort*       h1c    = h1h + (size_t)(p>=1?p-1:0)*32768;  // L1 output (p>=2)

    f32x4 accA0 = {0,0,0,0}, accA1 = {0,0,0,0};   // L1 accumulators (PRE+POST)

    // ================= PRE-barrier section =================
    // G0 prefetch for L0 cell (wave 0 only), deterministic via asm
    f32x2 pgI={0,0}, pgF={0,0}, pgG={0,0}, pgO={0,0};
    if(doL0 && tid < 64){
      const float* g0r = G0 + (size_t)(p*32+(tid>>1))*4096 + j0 + (tid&1)*2;
      asm volatile(
        "global_load_dwordx2 %0, %4, off\n\t"
        "global_load_dwordx2 %1, %5, off\n\t"
        "global_load_dwordx2 %2, %6, off\n\t"
        "global_load_dwordx2 %3, %7, off"
        : "=&v"(pgI), "=&v"(pgF), "=&v"(pgG), "=&v"(pgO)
        : "v"(g0r), "v"(g0r+1024), "v"(g0r+2048), "v"(g0r+3072)
        : "memory");
    }
    // L1 x-half: h0h[p-1] (old data, race-free pre-barrier), K-slice w*256
    {
      s4v ra[32];
      if(doL1){
        const char* ba = (const char*)h0prev + w*16384 + quad*512 + l16*8;
        load8(ba,       ra);
        load8(ba+4096,  ra+8);
        load8(ba+8192,  ra+16);
        load8(ba+12288, ra+24);
      }
      asm volatile("s_waitcnt vmcnt(0)" ::: "memory");   // drains PRE h + G0
      __builtin_amdgcn_sched_barrier(0);
      if(doL1){
        #pragma unroll
        for(int kc=0;kc<8;kc++){
          short8 af0 = __builtin_shufflevector(ra[kc*4+0], ra[kc*4+2], 0,1,2,3,4,5,6,7);
          short8 af1 = __builtin_shufflevector(ra[kc*4+1], ra[kc*4+3], 0,1,2,3,4,5,6,7);
          short8 bfrag = *(const short8*)&W1s[l16][w*256 + kc*32 + quad*8];
          accA0 = MFMA16(af0, bfrag, accA0);
          accA1 = MFMA16(af1, bfrag, accA1);
        }
      }
    }

    // ================= release wait (target p) =================
    if(p >= 1){
      const int target = p;
      if(blk==0 && tid<64){
        while(true){
          int mn = 0x7fffffff;
          #pragma unroll
          for(int q=0;q<8;q++){ int v = ALD(&flags[tid + q*64]); mn = min(mn, v); }
          if(__all(mn >= target)) break;
          __builtin_amdgcn_s_sleep(1);
        }
        if(tid < 16) AST(&flags[512 + tid*32], target);  // 16 release replicas
      }
      while(ALD(&flags[512 + (blk>>4)*32]) < target) __builtin_amdgcn_s_sleep(1);
    }

    // ================= POST-barrier section =================
    {
      s4v rb[32], rc[32];
      if(doL0){
        const char* bb = (const char*)h0p + w*16384 + quad*512 + l16*8;
        load8(bb,       rb);
        load8(bb+4096,  rb+8);
        load8(bb+8192,  rb+16);
        load8(bb+12288, rb+24);
      }
      if(doL1){
        const char* bc = (const char*)h1m + w*16384 + quad*512 + l16*8;
        load8(bc,       rc);
        load8(bc+4096,  rc+8);
        load8(bc+8192,  rc+16);
        load8(bc+12288, rc+24);
      }
      if(doL0){
        if(doL1) asm volatile("s_waitcnt vmcnt(32)" ::: "memory");  // L0's 32 done
        else     asm volatile("s_waitcnt vmcnt(0)"  ::: "memory");
        __builtin_amdgcn_sched_barrier(0);
        f32x4 acc0 = {0,0,0,0}, acc1 = {0,0,0,0};
        #pragma unroll
        for(int kc=0;kc<8;kc++){
          short8 af0 = __builtin_shufflevector(rb[kc*4+0], rb[kc*4+2], 0,1,2,3,4,5,6,7);
          short8 af1 = __builtin_shufflevector(rb[kc*4+1], rb[kc*4+3], 0,1,2,3,4,5,6,7);
          short8 bfrag = *(const short8*)&W0s[l16][w*256 + kc*32 + quad*8];
          acc0 = MFMA16(af0, bfrag, acc0);
          acc1 = MFMA16(af1, bfrag, acc1);
        }
        #pragma unroll
        for(int r=0;r<4;r++){
          gred0[par][w][quad*4+r][l16]    = acc0[r];
          gred0[par][w][16+quad*4+r][l16] = acc1[r];
        }
      }
      if(doL1){
        asm volatile("s_waitcnt vmcnt(0)" ::: "memory");
        __builtin_amdgcn_sched_barrier(0);
        #pragma unroll
        for(int kc=0;kc<8;kc++){
          short8 af0 = __builtin_shufflevector(rc[kc*4+0], rc[kc*4+2], 0,1,2,3,4,5,6,7);
          short8 af1 = __builtin_shufflevector(rc[kc*4+1], rc[kc*4+3], 0,1,2,3,4,5,6,7);
          short8 bfrag = *(const short8*)&W1s[l16][1024 + w*256 + kc*32 + quad*8];
          accA0 = MFMA16(af0, bfrag, accA0);
          accA1 = MFMA16(af1, bfrag, accA1);
        }
        #pragma unroll
        for(int r=0;r<4;r++){
          gred1[par][w][quad*4+r][l16]    = accA0[r];
          gred1[par][w][16+quad*4+r][l16] = accA1[r];
        }
      }
    }
    __syncthreads();   // gred[par] complete, visible to cell waves

    // ---- layer0 cell (wave 0), step p ----
    if(doL0 && tid < 64){
      int b = tid>>1, j2 = (tid&1)*2;
      ushort hv[2];
      #pragma unroll
      for(int u=0;u<2;u++){
        int jj = j2+u;
        float gi = u ? pgI.y : pgI.x;
        float gf = u ? pgF.y : pgF.x;
        float gg = u ? pgG.y : pgG.x;
        float go = u ? pgO.y : pgO.x;
        #pragma unroll
        for(int ww=0;ww<4;ww++){
          gi += gred0[par][ww][b][jj];    gf += gred0[par][ww][b][4+jj];
          gg += gred0[par][ww][b][8+jj];  go += gred0[par][ww][b][12+jj];
        }
        float c = cloc0[b][jj];
        float c1 = sigm(gf)*c + sigm(gi)*tanhf(gg);
        float h1 = sigm(go)*tanhf(c1);
        cloc0[b][jj] = c1;
        hv[u] = f2bf(h1);
        if(p==TDIM-1){
          outstate[b*1024 + j0 + jj] = h1;          // hT layer0
          outstate[65536 + b*1024 + j0 + jj] = c1;  // cT layer0
        }
      }
      uint pk = (uint)hv[0] | ((uint)hv[1] << 16);
      AST((uint*)(h0n + blk*128 + b*4 + j2), pk);   // block-major, line-exclusive
    }
    // ---- layer1 cell (wave 1), step t1 = p-2 ----
    if(doL1 && tid >= 64 && tid < 128){
      int ct = tid-64;
      int b = ct>>1, j2 = (ct&1)*2;
      ushort hv[2];
      #pragma unroll
      for(int u=0;u<2;u++){
        int jj = j2+u;
        float gi = u ? pbI.y : pbI.x;
        float gf = u ? pbF.y : pbF.x;
        float gg = u ? pbG.y : pbG.x;
        float go = u ? pbO.y : pbO.x;
        #pragma unroll
        for(int ww=0;ww<4;ww++){
          gi += gred1[par][ww][b][jj];    gf += gred1[par][ww][b][4+jj];
          gg += gred1[par][ww][b][8+jj];  go += gred1[par][ww][b][12+jj];
        }
        float c = cloc1[b][jj];
        float c1 = sigm(gf)*c + sigm(gi)*tanhf(gg);
        float h1 = sigm(go)*tanhf(c1);
        cloc1[b][jj] = c1;
        hv[u] = f2bf(h1);
        inp_bf[(size_t)((p-2)*32+b)*1024 + j0 + jj] = hv[u];
        if(p==TDIM+1){
          outstate[32768 + b*1024 + j0 + jj] = h1;          // hT layer1
          outstate[98304 + b*1024 + j0 + jj] = c1;          // cT layer1
        }
      }
      uint pk = (uint)hv[0] | ((uint)hv[1] << 16);
      AST((uint*)(h1c + blk*128 + b*4 + j2), pk);   // block-major, line-exclusive
    }
    if(p == TDIM+1) break;               // last phase: kernel end flushes

    // ---- per-wave arrival (waves 0,1 hold the cross-block h stores) ----
    if(tid < 128){
      asm volatile("s_waitcnt vmcnt(0)" ::: "memory");  // drain own sc1 h stores
      if((tid&63)==0) AST(&flags[blk*2 + w], p+1);
    }
  }
}

// ---------------- MFMA attention: block = (t-chunk of 16, b) ----------------
__global__ __launch_bounds__(256) void attn_mfma(
    const ushort* __restrict__ gamma_bf, // [2048][1024] rows t*32+b
    const ushort* __restrict__ ctxb,     // [32][64][1024] bf16
    const ushort* __restrict__ ctxT,     // [32][1024][64] bf16
    ushort* __restrict__ ctx_out){       // [2048][1024] bf16
  const int b = blockIdx.y, t0 = blockIdx.x*16;
  const int tid = threadIdx.x, w = tid>>6, lane = tid&63;
  const int quad = lane>>4, l16 = lane&15;
  __shared__ float S[16][68];
  __shared__ ushort Pb[16][72];
  {
    f32x4 acc = {0,0,0,0};
    const ushort* arow = gamma_bf + ((size_t)(t0+l16)*32 + b)*1024;
    const ushort* brow = ctxb + ((size_t)b*SDIM + w*16 + l16)*1024;
    #pragma unroll 8
    for(int kc=0;kc<32;kc++){
      short8 af = *(const short8*)(arow + kc*32 + quad*8);
      short8 bf = *(const short8*)(brow + kc*32 + quad*8);
      acc = MFMA16(af, bf, acc);
    }
    #pragma unroll
    for(int r=0;r<4;r++) S[quad*4+r][w*16+l16] = acc[r];
  }
  __syncthreads();
  if(tid < 16){
    float mx = -1e30f;
    for(int s=0;s<SDIM;s++) mx = fmaxf(mx, S[tid][s]);
    float sum = 0.f;
    for(int s=0;s<SDIM;s++) sum += expf(S[tid][s]-mx);
    float inv = 1.f/sum;
    for(int s=0;s<SDIM;s++) Pb[tid][s] = f2bf(expf(S[tid][s]-mx)*inv);
  }
  __syncthreads();
  const ushort* bbase = ctxT + ((size_t)b*HDIM + w*256)*SDIM;
  for(int nt=0; nt<16; nt++){
    f32x4 acc = {0,0,0,0};
    #pragma unroll
    for(int kc=0;kc<2;kc++){
      short8 af = *(const short8*)&Pb[l16][kc*32 + quad*8];
      short8 bf = *(const short8*)(bbase + (size_t)(nt*16+l16)*SDIM + kc*32 + quad*8);
      acc = MFMA16(af, bf, acc);
    }
    int n = w*256 + nt*16 + l16;
    #pragma unroll
    for(int r=0;r<4;r++){
      int t = t0 + quad*4 + r;
      ctx_out[((size_t)t*32 + b)*1024 + n] = f2bf(acc[r]);
    }
  }
}

extern "C" void kernel_launch(void* const* d_in, const int* in_sizes, int n_in,
                              void* d_out, int out_size, void* d_ws, size_t ws_size,
                              hipStream_t stream){
  const int*   tokens   = (const int*)  d_in[0];
  const float* h0       = (const float*)d_in[1];
  const float* c0       = (const float*)d_in[2];
  const float* contexts = (const float*)d_in[3];
  const float* emb      = (const float*)d_in[4];
  const float* W_ih     = (const float*)d_in[5];   // [2,4H,H]
  const float* W_hh     = (const float*)d_in[6];
  const float* b_ih     = (const float*)d_in[7];   // [2,4H]
  const float* b_hh     = (const float*)d_in[8];
  const float* W_in     = (const float*)d_in[9];   // [H,H]
  const float* b_in     = (const float*)d_in[10];
  const float* W_out    = (const float*)d_in[11];  // [H,2H]
  const float* b_out    = (const float*)d_in[12];

  float* out = (float*)d_out;
  const int TB = TDIM*BDIM;                        // 2048

  // ---- workspace layout ----
  char* wp = (char*)d_ws;
  float* G0      = (float*)wp;  wp += (size_t)TB*4*HDIM*4;          // 33.5 MB
  float* bias0c  = (float*)wp;  wp += 4096*4;
  float* bias1c  = (float*)wp;  wp += 4096*4;
  int*   flags   = (int*)wp;    wp += 4096;                         // 1024 ints
  ushort* X_bf   = (ushort*)wp; wp += (size_t)TB*HDIM*2;
  ushort* Wih0b  = (ushort*)wp; wp += (size_t)4*HDIM*HDIM*2;
  ushort* Whh0b  = (ushort*)wp; wp += (size_t)4*HDIM*HDIM*2;
  ushort* Wih1b  = (ushort*)wp; wp += (size_t)4*HDIM*HDIM*2;
  ushort* Whh1b  = (ushort*)wp; wp += (size_t)4*HDIM*HDIM*2;
  ushort* Winb   = (ushort*)wp; wp += (size_t)HDIM*HDIM*2;
  ushort* Woutb  = (ushort*)wp; wp += (size_t)HDIM*2*HDIM*2;
  ushort* inp_bf = (ushort*)wp; wp += (size_t)TB*HDIM*2;
  ushort* h0hist = (ushort*)wp; wp += (size_t)(TDIM+2)*BDIM*HDIM*2; // 66 x 64KB
  ushort* h1hist = (ushort*)wp; wp += (size_t)(TDIM+1)*BDIM*HDIM*2; // 65 x 64KB
  ushort* ctxb_bf= (ushort*)wp; wp += (size_t)BDIM*SDIM*HDIM*2;
  ushort* ctxT_bf= (ushort*)wp; wp += (size_t)BDIM*SDIM*HDIM*2;
  ushort* gammaB = (ushort*)G0;                                     // overlay
  ushort* ctx_bf = X_bf;                                            // overlay

  // ---- prep ----
  init_state_kernel<<<256,256,0,stream>>>(h0, h0hist, h1hist);
  bar_init_kernel<<<1,256,0,stream>>>(flags);
  fused_cast_kernel<<<21504,256,0,stream>>>(
      W_ih, W_hh, W_in, W_out, contexts,
      Wih0b, Whh0b, Wih1b, Whh1b, Winb, Woutb, ctxb_bf);
  transpose_ctx_kernel<<<dim3(16,32),256,0,stream>>>(contexts, ctxT_bf);
  bias_kernel<<<16,256,0,stream>>>(b_ih, b_hh, bias0c, bias1c);
  embed_kernel<<<TB,256,0,stream>>>(tokens, emb, X_bf);

  // ---- G0 = X @ Wih0^T + (b_ih0+b_hh0)  [2048,4096] fp32 ----
  gemm_mfma_bt<<<dim3(4*HDIM/64, TB/64),256,0,stream>>>(
      X_bf, X_bf, HDIM, HDIM, Wih0b, HDIM, bias0c, G0, 4*HDIM, HDIM, 0);

  // ---- skewed persistent scan (1 dispatch, 67 phases, 65 barriers) ----
  lstm_skew<<<NBLK,256,134656,stream>>>(
      Whh0b, Wih1b, Whh1b, G0, bias1c, c0,
      h0hist, h1hist, inp_bf, out + (size_t)TB*HDIM, flags);

  // ---- gamma = inp @ W_in^T + b_in -> bf16 (overlays G0) ----
  gemm_mfma_bt<<<dim3(HDIM/64, TB/64),256,0,stream>>>(
      inp_bf, inp_bf, HDIM, HDIM, Winb, HDIM, b_in, (float*)gammaB, HDIM, HDIM, 2);

  // ---- attention (MFMA) ----
  attn_mfma<<<dim3(4,32),256,0,stream>>>(gammaB, ctxb_bf, ctxT_bf, ctx_bf);

  // ---- out = tanh([ctx|inp] @ W_out^T + b_out) -> d_out ----
  gemm_mfma_bt<<<dim3(HDIM/64, TB/64),256,0,stream>>>(
      ctx_bf, inp_bf, HDIM, HDIM, Woutb, 2*HDIM, b_out, out, HDIM, 2*HDIM, 1);
}

// Round 7
// 780.881 us; speedup vs baseline: 2.3503x; 1.0502x over previous
//
#include <hip/hip_runtime.h>
#include <hip/hip_bf16.h>

#define HDIM 1024
#define BDIM 32
#define TDIM 64
#define SDIM 64
#define NBLK 256

typedef __attribute__((ext_vector_type(8))) short short8;
typedef __attribute__((ext_vector_type(4))) short s4v;
typedef __attribute__((ext_vector_type(4))) float f32x4;
typedef __attribute__((ext_vector_type(2))) float f32x2;
typedef unsigned short ushort;
typedef unsigned int uint;

__device__ __forceinline__ float sigm(float x){ return 1.f/(1.f+expf(-x)); }
__device__ __forceinline__ ushort f2bf(float x){
  uint u = __float_as_uint(x);
  u = (u + 0x7FFF + ((u>>16)&1)) >> 16;   // RNE
  return (ushort)u;
}
#define MFMA16(a,b,c) __builtin_amdgcn_mfma_f32_16x16x32_bf16((a),(b),(c),0,0,0)
#define ALD(p)     __hip_atomic_load((p), __ATOMIC_RELAXED, __HIP_MEMORY_SCOPE_AGENT)
#define AST(p,v)   __hip_atomic_store((p),(v), __ATOMIC_RELAXED, __HIP_MEMORY_SCOPE_AGENT)

// Batched h-fragment loader: 8 plain-cached 8B loads from one wave-uniform
// base + imm offsets. Loads stay in flight; caller inserts the s_waitcnt +
// sched_barrier(0) (rule #18) before consumption.
__device__ __forceinline__ void load8(const char* b, s4v* r){
  asm volatile(
    "global_load_dwordx2 %0, %8, off\n\t"
    "global_load_dwordx2 %1, %8, off offset:128\n\t"
    "global_load_dwordx2 %2, %8, off offset:256\n\t"
    "global_load_dwordx2 %3, %8, off offset:384\n\t"
    "global_load_dwordx2 %4, %8, off offset:2048\n\t"
    "global_load_dwordx2 %5, %8, off offset:2176\n\t"
    "global_load_dwordx2 %6, %8, off offset:2304\n\t"
    "global_load_dwordx2 %7, %8, off offset:2432\n\t"
    : "=&v"(r[0]), "=&v"(r[1]), "=&v"(r[2]), "=&v"(r[3]),
      "=&v"(r[4]), "=&v"(r[5]), "=&v"(r[6]), "=&v"(r[7])
    : "v"(b) : "memory");
}

// h history layout (block-major, line-exclusive): state = [256 blocks][32 b][4 cols]
// ushort idx within a 32768-ushort state: blk*128 + b*4 + jj.

// ---------------- init: bf16 h seeds into history slot 0 ----------------
__global__ void init_state_kernel(const float* __restrict__ h0,
                                  ushort* __restrict__ h0h,
                                  ushort* __restrict__ h1h){
  int i = blockIdx.x*256 + threadIdx.x;       // 0..65535
  int l = i >> 15, r = i & 32767;             // r = b*1024 + h
  int b = r >> 10, h = r & 1023;
  ushort* dst = l ? h1h : h0h;
  dst[(h>>2)*128 + b*4 + (h&3)] = f2bf(h0[i]);
}

__global__ void bar_init_kernel(int* flags){
  for(int i=threadIdx.x; i<1024; i+=256) flags[i] = 0;  // arrivals [0..511], release replicas [512..1023]
}

// ---------------- fused fp32 -> bf16 cast: all 7 segments, one launch ----------------
// prefix sums (float4 units): Wih0 1048576 | Whh0 1048576 | Wih1 1048576 |
// Whh1 1048576 | Win 262144 | Wout 524288 | ctx 524288  => total 5505024 = 21504*256
__global__ void fused_cast_kernel(
    const float* __restrict__ W_ih, const float* __restrict__ W_hh,
    const float* __restrict__ W_in, const float* __restrict__ W_out,
    const float* __restrict__ ctx,
    ushort* __restrict__ Wih0b, ushort* __restrict__ Whh0b,
    ushort* __restrict__ Wih1b, ushort* __restrict__ Whh1b,
    ushort* __restrict__ Winb,  ushort* __restrict__ Woutb,
    ushort* __restrict__ ctxb){
  long i = (long)blockIdx.x*256 + threadIdx.x;
  const float* src; ushort* dst; long off;
  if(i < 2097152){
    if(i < 1048576){ src=W_ih;          dst=Wih0b; off=i; }
    else           { src=W_hh;          dst=Whh0b; off=i-1048576; }
  } else if(i < 4194304){
    if(i < 3145728){ src=W_ih+4194304;  dst=Wih1b; off=i-2097152; }
    else           { src=W_hh+4194304;  dst=Whh1b; off=i-3145728; }
  } else if(i < 4456448){ src=W_in;     dst=Winb;  off=i-4194304; }
  else if(i < 4980736){   src=W_out;    dst=Woutb; off=i-4456448; }
  else {                  src=ctx;      dst=ctxb;  off=i-4980736; }
  float4 v = ((const float4*)src)[off];
  ushort4 o; o.x=f2bf(v.x); o.y=f2bf(v.y); o.z=f2bf(v.z); o.w=f2bf(v.w);
  ((ushort4*)dst)[off] = o;
}

// ---------------- contexts transpose: [32][64][1024] f32 -> [32][1024][64] bf16 ----
__global__ void transpose_ctx_kernel(const float* __restrict__ ctx, ushort* __restrict__ ctxT){
  int b = blockIdx.y;
  int n = blockIdx.x*64 + (threadIdx.x & 63);
  int s0 = (threadIdx.x >> 6) * 16;
  for(int s=s0; s<s0+16; s++){
    float v = ctx[((size_t)b*SDIM + s)*HDIM + n];
    ctxT[((size_t)b*HDIM + n)*SDIM + s] = f2bf(v);
  }
}

// ---------------- combined biases ----------------
__global__ void bias_kernel(const float* __restrict__ b_ih, const float* __restrict__ b_hh,
                            float* __restrict__ bias0, float* __restrict__ bias1){
  int i = blockIdx.x*256 + threadIdx.x;   // 0..4095
  bias0[i] = b_ih[i] + b_hh[i];
  bias1[i] = b_ih[4096+i] + b_hh[4096+i];
}

// ---------------- embedding gather + bf16 cast ----------------
__global__ void embed_kernel(const int* __restrict__ tokens,
                             const float* __restrict__ emb,
                             ushort* __restrict__ Xb){
  int tb = blockIdx.x;
  int tok = tokens[tb];
  const float4* src = (const float4*)(emb + (size_t)tok*HDIM);
  ushort4* dst = (ushort4*)(Xb + (size_t)tb*HDIM);
  float4 v = src[threadIdx.x];
  ushort4 o; o.x=f2bf(v.x); o.y=f2bf(v.y); o.z=f2bf(v.z); o.w=f2bf(v.w);
  dst[threadIdx.x] = o;
}

// ---------------- 128x128 MFMA GEMM: C = act(A@B^T + bias) ----------------
// Register-staged double-buffer: K-tile k+32 prefetched into regs during the
// MFMAs of tile k (global latency hidden under compute). 4 waves, each owns a
// 64x64 quadrant: 16 MFMA/wave per K-step (4x the old 64^2 kernel's ratio).
// LDS [128][40] pad: ds_read row-pair aliasing 2-way (free); staging writes
// 2-way (free). act: 0 = fp32 store, 1 = tanh fp32, 2 = bf16 store.
__global__ __launch_bounds__(256) void gemm128(
    const ushort* __restrict__ A0, const ushort* __restrict__ A1, int lda, int KSPLIT,
    const ushort* __restrict__ B, int ldb,
    const float* __restrict__ bias,
    float* __restrict__ C, int ldc, int K, int act){
  __shared__ ushort As[128][40];
  __shared__ ushort Bs[128][40];
  const int bm = blockIdx.y*128, bn = blockIdx.x*128;
  const int tid = threadIdx.x, w = tid>>6, lane = tid&63;
  const int quad = lane>>4, l16 = lane&15;
  const int wr = (w>>1)*64, wc = (w&1)*64;     // wave's 64x64 quadrant
  const int srow = tid>>2, sseg = (tid&3)*8;   // staging: 4 threads/row, 16B each
  f32x4 acc[4][4];
  #pragma unroll
  for(int i=0;i<4;i++)
    #pragma unroll
    for(int j=0;j<4;j++) acc[i][j] = (f32x4){0.f,0.f,0.f,0.f};

  float4 ra0, ra1, rb0, rb1;
  {
    int gk = sseg;
    const ushort* ap = (gk < KSPLIT) ? (A0 + (size_t)(bm+srow)*lda + gk)
                                     : (A1 + (size_t)(bm+srow)*lda + (gk-KSPLIT));
    ra0 = *(const float4*)ap;  ra1 = *(const float4*)(ap + (size_t)64*lda);
    const ushort* bp = B + (size_t)(bn+srow)*ldb + gk;
    rb0 = *(const float4*)bp;  rb1 = *(const float4*)(bp + (size_t)64*ldb);
  }
  for(int k0=0;k0<K;k0+=32){
    __syncthreads();                       // prior readers done
    *(float4*)&As[srow][sseg]    = ra0;
    *(float4*)&As[srow+64][sseg] = ra1;
    *(float4*)&Bs[srow][sseg]    = rb0;
    *(float4*)&Bs[srow+64][sseg] = rb1;
    __syncthreads();                       // tile ready
    if(k0+32 < K){                         // prefetch next tile (hides under MFMA)
      int gk = k0 + 32 + sseg;
      const ushort* ap = (gk < KSPLIT) ? (A0 + (size_t)(bm+srow)*lda + gk)
                                       : (A1 + (size_t)(bm+srow)*lda + (gk-KSPLIT));
      ra0 = *(const float4*)ap;  ra1 = *(const float4*)(ap + (size_t)64*lda);
      const ushort* bp = B + (size_t)(bn+srow)*ldb + k0 + 32 + sseg;
      rb0 = *(const float4*)bp;  rb1 = *(const float4*)(bp + (size_t)64*ldb);
    }
    short8 af[4], bf[4];
    #pragma unroll
    for(int mi=0;mi<4;mi++) af[mi] = *(const short8*)&As[wr+mi*16+l16][quad*8];
    #pragma unroll
    for(int ni=0;ni<4;ni++) bf[ni] = *(const short8*)&Bs[wc+ni*16+l16][quad*8];
    #pragma unroll
    for(int mi=0;mi<4;mi++)
      #pragma unroll
      for(int ni=0;ni<4;ni++)
        acc[mi][ni] = MFMA16(af[mi], bf[ni], acc[mi][ni]);
  }
  #pragma unroll
  for(int mi=0;mi<4;mi++){
    #pragma unroll
    for(int r=0;r<4;r++){
      int row = bm + wr + mi*16 + quad*4 + r;
      #pragma unroll
      for(int ni=0;ni<4;ni++){
        int col = bn + wc + ni*16 + l16;
        float v = acc[mi][ni][r];
        if(bias) v += bias[col];
        if(act==1) v = tanhf(v);
        if(act==2) ((ushort*)C)[(size_t)row*ldc + col] = f2bf(v);
        else       C[(size_t)row*ldc + col] = v;
      }
    }
  }
}

// ---------------- skewed persistent LSTM scan (skew-2) ----------------
// r6 kernel VERBATIM (unchanged this round for clean attribution).
__global__ __launch_bounds__(256,1) void lstm_skew(
    const ushort* __restrict__ Whh0b,   // [4096][1024] bf16
    const ushort* __restrict__ Wih1b,   // [4096][1024]
    const ushort* __restrict__ Whh1b,   // [4096][1024]
    const float*  __restrict__ G0,      // [T*32][4096] fp32 (bias0 folded)
    const float*  __restrict__ bias1c,  // [4096]
    const float*  __restrict__ c0in,    // [2][32][1024]
    ushort* __restrict__ h0h,           // [66][32768] block-major h0 states
    ushort* __restrict__ h1h,           // [65][32768] block-major h1 states
    ushort* __restrict__ inp_bf,        // [T*32][1024]
    float*  __restrict__ outstate,      // h[2][32][1024] then c[2][32][1024]
    int* __restrict__ flags){           // [1024]: [0..511] arrivals (2/blk), [512+32r] release replicas
  extern __shared__ char smem[];
  ushort (*W0s)[1032]   = (ushort(*)[1032])smem;                   // 33024 B
  ushort (*W1s)[2056]   = (ushort(*)[2056])(smem + 33024);         // 65792 B
  typedef float gredT[4][32][17];                                  // 8704 B each
  gredT* gred0 = (gredT*)(smem + 98816);                           // [2] parity
  gredT* gred1 = (gredT*)(smem + 116224);                          // [2] parity
  float (*cloc0)[4]      = (float(*)[4])(smem + 133632);           // 512 B
  float (*cloc1)[4]      = (float(*)[4])(smem + 134144);           // 512 B

  const int tid = threadIdx.x, w = tid>>6, lane = tid&63;
  const int quad = lane>>4, l16 = lane&15;
  const int blk = blockIdx.x;
  const int j0 = blk*4;

  // ---- load weight slices into LDS (held for all phases) — r4 verbatim ----
  {
    int r = tid>>4, seg = tid&15;                       // 16 rows x 16 segments
    int wr = (r>>2)*1024 + j0 + (r&3);                  // gate-major weight row
    const ushort* s0 = Whh0b + (size_t)wr*1024 + seg*64;
    const ushort* s1 = Wih1b + (size_t)wr*1024 + seg*64;
    const ushort* s2 = Whh1b + (size_t)wr*1024 + seg*64;
    #pragma unroll
    for(int u=0; u<64; u+=8){
      *(short8*)&W0s[r][seg*64+u]       = *(const short8*)(s0+u);
      *(short8*)&W1s[r][seg*64+u]       = *(const short8*)(s1+u);
      *(short8*)&W1s[r][1024+seg*64+u]  = *(const short8*)(s2+u);
    }
  }
  if(tid < 128){
    int b = tid>>2, jj = tid&3;
    cloc0[b][jj] = c0in[b*1024 + j0 + jj];
    cloc1[b][jj] = c0in[32768 + b*1024 + j0 + jj];
  }
  // loop-invariant bias1 in registers (layer-1 cell threads: tid 64..127)
  float2 pbI={0,0}, pbF={0,0}, pbG={0,0}, pbO={0,0};
  if(tid >= 64 && tid < 128){
    const float* br = bias1c + j0 + ((tid-64)&1)*2;
    pbI = *(const float2*)(br);
    pbF = *(const float2*)(br+1024);
    pbG = *(const float2*)(br+2048);
    pbO = *(const float2*)(br+3072);
  }
  __syncthreads();

  for(int p=0; p<=TDIM+1; p++){
    const int par = p&1;
    const bool doL0 = (p < TDIM);
    const bool doL1 = (p >= 2);
    const ushort* h0p    = h0h + (size_t)p*32768;             // L0 input (POST)
    ushort*       h0n    = h0h + (size_t)(p+1)*32768;         // L0 output
    const ushort* h0prev = h0h + (size_t)(p>=1?p-1:0)*32768;  // L1 x-input (PRE)
    const ushort* h1m    = h1h + (size_t)(p>=2?p-2:0)*32768;  // L1 state input (POST)
    ushort*       h1c    = h1h + (size_t)(p>=1?p-1:0)*32768;  // L1 output (p>=2)

    f32x4 accA0 = {0,0,0,0}, accA1 = {0,0,0,0};   // L1 accumulators (PRE+POST)

    // ================= PRE-barrier section =================
    // G0 prefetch for L0 cell (wave 0 only), deterministic via asm
    f32x2 pgI={0,0}, pgF={0,0}, pgG={0,0}, pgO={0,0};
    if(doL0 && tid < 64){
      const float* g0r = G0 + (size_t)(p*32+(tid>>1))*4096 + j0 + (tid&1)*2;
      asm volatile(
        "global_load_dwordx2 %0, %4, off\n\t"
        "global_load_dwordx2 %1, %5, off\n\t"
        "global_load_dwordx2 %2, %6, off\n\t"
        "global_load_dwordx2 %3, %7, off"
        : "=&v"(pgI), "=&v"(pgF), "=&v"(pgG), "=&v"(pgO)
        : "v"(g0r), "v"(g0r+1024), "v"(g0r+2048), "v"(g0r+3072)
        : "memory");
    }
    // L1 x-half: h0h[p-1] (old data, race-free pre-barrier), K-slice w*256
    {
      s4v ra[32];
      if(doL1){
        const char* ba = (const char*)h0prev + w*16384 + quad*512 + l16*8;
        load8(ba,       ra);
        load8(ba+4096,  ra+8);
        load8(ba+8192,  ra+16);
        load8(ba+12288, ra+24);
      }
      asm volatile("s_waitcnt vmcnt(0)" ::: "memory");   // drains PRE h + G0
      __builtin_amdgcn_sched_barrier(0);
      if(doL1){
        #pragma unroll
        for(int kc=0;kc<8;kc++){
          short8 af0 = __builtin_shufflevector(ra[kc*4+0], ra[kc*4+2], 0,1,2,3,4,5,6,7);
          short8 af1 = __builtin_shufflevector(ra[kc*4+1], ra[kc*4+3], 0,1,2,3,4,5,6,7);
          short8 bfrag = *(const short8*)&W1s[l16][w*256 + kc*32 + quad*8];
          accA0 = MFMA16(af0, bfrag, accA0);
          accA1 = MFMA16(af1, bfrag, accA1);
        }
      }
    }

    // ================= release wait (target p) =================
    if(p >= 1){
      const int target = p;
      if(blk==0 && tid<64){
        while(true){
          int mn = 0x7fffffff;
          #pragma unroll
          for(int q=0;q<8;q++){ int v = ALD(&flags[tid + q*64]); mn = min(mn, v); }
          if(__all(mn >= target)) break;
          __builtin_amdgcn_s_sleep(1);
        }
        if(tid < 16) AST(&flags[512 + tid*32], target);  // 16 release replicas
      }
      while(ALD(&flags[512 + (blk>>4)*32]) < target) __builtin_amdgcn_s_sleep(1);
    }

    // ================= POST-barrier section =================
    {
      s4v rb[32], rc[32];
      if(doL0){
        const char* bb = (const char*)h0p + w*16384 + quad*512 + l16*8;
        load8(bb,       rb);
        load8(bb+4096,  rb+8);
        load8(bb+8192,  rb+16);
        load8(bb+12288, rb+24);
      }
      if(doL1){
        const char* bc = (const char*)h1m + w*16384 + quad*512 + l16*8;
        load8(bc,       rc);
        load8(bc+4096,  rc+8);
        load8(bc+8192,  rc+16);
        load8(bc+12288, rc+24);
      }
      if(doL0){
        if(doL1) asm volatile("s_waitcnt vmcnt(32)" ::: "memory");  // L0's 32 done
        else     asm volatile("s_waitcnt vmcnt(0)"  ::: "memory");
        __builtin_amdgcn_sched_barrier(0);
        f32x4 acc0 = {0,0,0,0}, acc1 = {0,0,0,0};
        #pragma unroll
        for(int kc=0;kc<8;kc++){
          short8 af0 = __builtin_shufflevector(rb[kc*4+0], rb[kc*4+2], 0,1,2,3,4,5,6,7);
          short8 af1 = __builtin_shufflevector(rb[kc*4+1], rb[kc*4+3], 0,1,2,3,4,5,6,7);
          short8 bfrag = *(const short8*)&W0s[l16][w*256 + kc*32 + quad*8];
          acc0 = MFMA16(af0, bfrag, acc0);
          acc1 = MFMA16(af1, bfrag, acc1);
        }
        #pragma unroll
        for(int r=0;r<4;r++){
          gred0[par][w][quad*4+r][l16]    = acc0[r];
          gred0[par][w][16+quad*4+r][l16] = acc1[r];
        }
      }
      if(doL1){
        asm volatile("s_waitcnt vmcnt(0)" ::: "memory");
        __builtin_amdgcn_sched_barrier(0);
        #pragma unroll
        for(int kc=0;kc<8;kc++){
          short8 af0 = __builtin_shufflevector(rc[kc*4+0], rc[kc*4+2], 0,1,2,3,4,5,6,7);
          short8 af1 = __builtin_shufflevector(rc[kc*4+1], rc[kc*4+3], 0,1,2,3,4,5,6,7);
          short8 bfrag = *(const short8*)&W1s[l16][1024 + w*256 + kc*32 + quad*8];
          accA0 = MFMA16(af0, bfrag, accA0);
          accA1 = MFMA16(af1, bfrag, accA1);
        }
        #pragma unroll
        for(int r=0;r<4;r++){
          gred1[par][w][quad*4+r][l16]    = accA0[r];
          gred1[par][w][16+quad*4+r][l16] = accA1[r];
        }
      }
    }
    __syncthreads();   // gred[par] complete, visible to cell waves

    // ---- layer0 cell (wave 0), step p ----
    if(doL0 && tid < 64){
      int b = tid>>1, j2 = (tid&1)*2;
      ushort hv[2];
      #pragma unroll
      for(int u=0;u<2;u++){
        int jj = j2+u;
        float gi = u ? pgI.y : pgI.x;
        float gf = u ? pgF.y : pgF.x;
        float gg = u ? pgG.y : pgG.x;
        float go = u ? pgO.y : pgO.x;
        #pragma unroll
        for(int ww=0;ww<4;ww++){
          gi += gred0[par][ww][b][jj];    gf += gred0[par][ww][b][4+jj];
          gg += gred0[par][ww][b][8+jj];  go += gred0[par][ww][b][12+jj];
        }
        float c = cloc0[b][jj];
        float c1 = sigm(gf)*c + sigm(gi)*tanhf(gg);
        float h1 = sigm(go)*tanhf(c1);
        cloc0[b][jj] = c1;
        hv[u] = f2bf(h1);
        if(p==TDIM-1){
          outstate[b*1024 + j0 + jj] = h1;          // hT layer0
          outstate[65536 + b*1024 + j0 + jj] = c1;  // cT layer0
        }
      }
      uint pk = (uint)hv[0] | ((uint)hv[1] << 16);
      AST((uint*)(h0n + blk*128 + b*4 + j2), pk);   // block-major, line-exclusive
    }
    // ---- layer1 cell (wave 1), step t1 = p-2 ----
    if(doL1 && tid >= 64 && tid < 128){
      int ct = tid-64;
      int b = ct>>1, j2 = (ct&1)*2;
      ushort hv[2];
      #pragma unroll
      for(int u=0;u<2;u++){
        int jj = j2+u;
        float gi = u ? pbI.y : pbI.x;
        float gf = u ? pbF.y : pbF.x;
        float gg = u ? pbG.y : pbG.x;
        float go = u ? pbO.y : pbO.x;
        #pragma unroll
        for(int ww=0;ww<4;ww++){
          gi += gred1[par][ww][b][jj];    gf += gred1[par][ww][b][4+jj];
          gg += gred1[par][ww][b][8+jj];  go += gred1[par][ww][b][12+jj];
        }
        float c = cloc1[b][jj];
        float c1 = sigm(gf)*c + sigm(gi)*tanhf(gg);
        float h1 = sigm(go)*tanhf(c1);
        cloc1[b][jj] = c1;
        hv[u] = f2bf(h1);
        inp_bf[(size_t)((p-2)*32+b)*1024 + j0 + jj] = hv[u];
        if(p==TDIM+1){
          outstate[32768 + b*1024 + j0 + jj] = h1;          // hT layer1
          outstate[98304 + b*1024 + j0 + jj] = c1;          // cT layer1
        }
      }
      uint pk = (uint)hv[0] | ((uint)hv[1] << 16);
      AST((uint*)(h1c + blk*128 + b*4 + j2), pk);   // block-major, line-exclusive
    }
    if(p == TDIM+1) break;               // last phase: kernel end flushes

    // ---- per-wave arrival (waves 0,1 hold the cross-block h stores) ----
    if(tid < 128){
      asm volatile("s_waitcnt vmcnt(0)" ::: "memory");  // drain own sc1 h stores
      if((tid&63)==0) AST(&flags[blk*2 + w], p+1);
    }
  }
}

// ---------------- MFMA attention: block = (t-chunk of 16, b) ----------------
__global__ __launch_bounds__(256) void attn_mfma(
    const ushort* __restrict__ gamma_bf, // [2048][1024] rows t*32+b
    const ushort* __restrict__ ctxb,     // [32][64][1024] bf16
    const ushort* __restrict__ ctxT,     // [32][1024][64] bf16
    ushort* __restrict__ ctx_out){       // [2048][1024] bf16
  const int b = blockIdx.y, t0 = blockIdx.x*16;
  const int tid = threadIdx.x, w = tid>>6, lane = tid&63;
  const int quad = lane>>4, l16 = lane&15;
  __shared__ float S[16][68];
  __shared__ ushort Pb[16][72];
  {
    f32x4 acc = {0,0,0,0};
    const ushort* arow = gamma_bf + ((size_t)(t0+l16)*32 + b)*1024;
    const ushort* brow = ctxb + ((size_t)b*SDIM + w*16 + l16)*1024;
    #pragma unroll 8
    for(int kc=0;kc<32;kc++){
      short8 af = *(const short8*)(arow + kc*32 + quad*8);
      short8 bf = *(const short8*)(brow + kc*32 + quad*8);
      acc = MFMA16(af, bf, acc);
    }
    #pragma unroll
    for(int r=0;r<4;r++) S[quad*4+r][w*16+l16] = acc[r];
  }
  __syncthreads();
  if(tid < 16){
    float mx = -1e30f;
    for(int s=0;s<SDIM;s++) mx = fmaxf(mx, S[tid][s]);
    float sum = 0.f;
    for(int s=0;s<SDIM;s++) sum += expf(S[tid][s]-mx);
    float inv = 1.f/sum;
    for(int s=0;s<SDIM;s++) Pb[tid][s] = f2bf(expf(S[tid][s]-mx)*inv);
  }
  __syncthreads();
  const ushort* bbase = ctxT + ((size_t)b*HDIM + w*256)*SDIM;
  for(int nt=0; nt<16; nt++){
    f32x4 acc = {0,0,0,0};
    #pragma unroll
    for(int kc=0;kc<2;kc++){
      short8 af = *(const short8*)&Pb[l16][kc*32 + quad*8];
      short8 bf = *(const short8*)(bbase + (size_t)(nt*16+l16)*SDIM + kc*32 + quad*8);
      acc = MFMA16(af, bf, acc);
    }
    int n = w*256 + nt*16 + l16;
    #pragma unroll
    for(int r=0;r<4;r++){
      int t = t0 + quad*4 + r;
      ctx_out[((size_t)t*32 + b)*1024 + n] = f2bf(acc[r]);
    }
  }
}

extern "C" void kernel_launch(void* const* d_in, const int* in_sizes, int n_in,
                              void* d_out, int out_size, void* d_ws, size_t ws_size,
                              hipStream_t stream){
  const int*   tokens   = (const int*)  d_in[0];
  const float* h0       = (const float*)d_in[1];
  const float* c0       = (const float*)d_in[2];
  const float* contexts = (const float*)d_in[3];
  const float* emb      = (const float*)d_in[4];
  const float* W_ih     = (const float*)d_in[5];   // [2,4H,H]
  const float* W_hh     = (const float*)d_in[6];
  const float* b_ih     = (const float*)d_in[7];   // [2,4H]
  const float* b_hh     = (const float*)d_in[8];
  const float* W_in     = (const float*)d_in[9];   // [H,H]
  const float* b_in     = (const float*)d_in[10];
  const float* W_out    = (const float*)d_in[11];  // [H,2H]
  const float* b_out    = (const float*)d_in[12];

  float* out = (float*)d_out;
  const int TB = TDIM*BDIM;                        // 2048

  // ---- workspace layout ----
  char* wp = (char*)d_ws;
  float* G0      = (float*)wp;  wp += (size_t)TB*4*HDIM*4;          // 33.5 MB
  float* bias0c  = (float*)wp;  wp += 4096*4;
  float* bias1c  = (float*)wp;  wp += 4096*4;
  int*   flags   = (int*)wp;    wp += 4096;                         // 1024 ints
  ushort* X_bf   = (ushort*)wp; wp += (size_t)TB*HDIM*2;
  ushort* Wih0b  = (ushort*)wp; wp += (size_t)4*HDIM*HDIM*2;
  ushort* Whh0b  = (ushort*)wp; wp += (size_t)4*HDIM*HDIM*2;
  ushort* Wih1b  = (ushort*)wp; wp += (size_t)4*HDIM*HDIM*2;
  ushort* Whh1b  = (ushort*)wp; wp += (size_t)4*HDIM*HDIM*2;
  ushort* Winb   = (ushort*)wp; wp += (size_t)HDIM*HDIM*2;
  ushort* Woutb  = (ushort*)wp; wp += (size_t)HDIM*2*HDIM*2;
  ushort* inp_bf = (ushort*)wp; wp += (size_t)TB*HDIM*2;
  ushort* h0hist = (ushort*)wp; wp += (size_t)(TDIM+2)*BDIM*HDIM*2; // 66 x 64KB
  ushort* h1hist = (ushort*)wp; wp += (size_t)(TDIM+1)*BDIM*HDIM*2; // 65 x 64KB
  ushort* ctxb_bf= (ushort*)wp; wp += (size_t)BDIM*SDIM*HDIM*2;
  ushort* ctxT_bf= (ushort*)wp; wp += (size_t)BDIM*SDIM*HDIM*2;
  ushort* gammaB = (ushort*)G0;                                     // overlay
  ushort* ctx_bf = X_bf;                                            // overlay

  // ---- prep ----
  init_state_kernel<<<256,256,0,stream>>>(h0, h0hist, h1hist);
  bar_init_kernel<<<1,256,0,stream>>>(flags);
  fused_cast_kernel<<<21504,256,0,stream>>>(
      W_ih, W_hh, W_in, W_out, contexts,
      Wih0b, Whh0b, Wih1b, Whh1b, Winb, Woutb, ctxb_bf);
  transpose_ctx_kernel<<<dim3(16,32),256,0,stream>>>(contexts, ctxT_bf);
  bias_kernel<<<16,256,0,stream>>>(b_ih, b_hh, bias0c, bias1c);
  embed_kernel<<<TB,256,0,stream>>>(tokens, emb, X_bf);

  // ---- G0 = X @ Wih0^T + (b_ih0+b_hh0)  [2048,4096] fp32 ----
  gemm128<<<dim3(4*HDIM/128, TB/128),256,0,stream>>>(
      X_bf, X_bf, HDIM, HDIM, Wih0b, HDIM, bias0c, G0, 4*HDIM, HDIM, 0);

  // ---- skewed persistent scan (1 dispatch, 67 phases, 66 barriers) ----
  lstm_skew<<<NBLK,256,134656,stream>>>(
      Whh0b, Wih1b, Whh1b, G0, bias1c, c0,
      h0hist, h1hist, inp_bf, out + (size_t)TB*HDIM, flags);

  // ---- gamma = inp @ W_in^T + b_in -> bf16 (overlays G0) ----
  gemm128<<<dim3(HDIM/128, TB/128),256,0,stream>>>(
      inp_bf, inp_bf, HDIM, HDIM, Winb, HDIM, b_in, (float*)gammaB, HDIM, HDIM, 2);

  // ---- attention (MFMA) ----
  attn_mfma<<<dim3(4,32),256,0,stream>>>(gammaB, ctxb_bf, ctxT_bf, ctx_bf);

  // ---- out = tanh([ctx|inp] @ W_out^T + b_out) -> d_out ----
  gemm128<<<dim3(HDIM/128, TB/128),256,0,stream>>>(
      ctx_bf, inp_bf, HDIM, HDIM, Woutb, 2*HDIM, b_out, out, HDIM, 2*HDIM, 1);
}